// Round 2
// baseline (62517.688 us; speedup 1.0000x reference)
//
#include <hip/hip_runtime.h>
#include <hip/hip_bf16.h>

// GeRN fused: kernel1 precomputes static (cnd/qry) contributions to all 4 LSTM
// gate pre-activations; kernel2 runs the 12-step recurrence fused per block
// (16 batch rows/block, thread = (hidden unit h, row-group)), states in LDS.
// eps replicates JAX threefry2x32 in PARTITIONABLE counter mode (default since
// jax 0.4.36): x0=hi32(i)=0, x1=lo32(i), bits = out0 ^ out1.

#define NROW 4      // rows per thread-group (recurrent kernel)
#define RROWS 16    // rows per block (both kernels)

__device__ __forceinline__ float sigmoidf_(float x) {
  return 1.0f / (1.0f + __expf(-x));
}

// --- JAX threefry2x32-20 (partitionable) + uniform + XLA ErfInv32 (Giles) ---
__device__ __forceinline__ float eps_threefry(unsigned seed, unsigned idx) {
  unsigned x0 = 0u, x1 = idx;
  const unsigned ks0 = 0u, ks1 = seed, ks2 = seed ^ 0x1BD11BDAu; // k0^k1^C
  x0 += ks0; x1 += ks1;
#define TF_R(r) { x0 += x1; x1 = (x1 << (r)) | (x1 >> (32 - (r))); x1 ^= x0; }
  TF_R(13) TF_R(15) TF_R(26) TF_R(6)  x0 += ks1; x1 += ks2 + 1u;
  TF_R(17) TF_R(29) TF_R(16) TF_R(24) x0 += ks2; x1 += ks0 + 2u;
  TF_R(13) TF_R(15) TF_R(26) TF_R(6)  x0 += ks0; x1 += ks1 + 3u;
  TF_R(17) TF_R(29) TF_R(16) TF_R(24) x0 += ks1; x1 += ks2 + 4u;
  TF_R(13) TF_R(15) TF_R(26) TF_R(6)  x0 += ks2; x1 += ks0 + 5u;
#undef TF_R
  unsigned bits = x0 ^ x1;   // partitionable 32-bit fold
  unsigned fb = (bits >> 9) | 0x3F800000u;          // [1,2)
  const float lo = -0.99999994f;                    // nextafter(-1,0)
  float f = __uint_as_float(fb) - 1.0f;             // [0,1)
  float u = fmaxf(lo, f * 2.0f + lo);               // (hi-lo) rounds to 2.0f
  float w = -log1pf(-u * u);
  float p;
  if (w < 5.0f) {
    w -= 2.5f;
    p = 2.81022636e-08f;
    p = fmaf(p, w, 3.43273939e-07f);
    p = fmaf(p, w, -3.5233877e-06f);
    p = fmaf(p, w, -4.39150654e-06f);
    p = fmaf(p, w, 0.00021858087f);
    p = fmaf(p, w, -0.00125372503f);
    p = fmaf(p, w, -0.00417768164f);
    p = fmaf(p, w, 0.246640727f);
    p = fmaf(p, w, 1.50140941f);
  } else {
    w = sqrtf(w) - 3.0f;
    p = -0.000200214257f;
    p = fmaf(p, w, 0.000100950558f);
    p = fmaf(p, w, 0.00134934322f);
    p = fmaf(p, w, -0.00367342844f);
    p = fmaf(p, w, 0.00573950773f);
    p = fmaf(p, w, -0.0076224613f);
    p = fmaf(p, w, 0.00943887047f);
    p = fmaf(p, w, 1.00167406f);
    p = fmaf(p, w, 2.83297682f);
  }
  return 1.41421356f * (p * u); // sqrt(2)_f32 * erfinv(u)
}

// ================= Kernel 1: static precompute =================
// pre_X[b][c] = b_X[c] + static-rows(x) @ W_X[:,c], for the 4 LSTMs.
template<int LDW>
__device__ __forceinline__ void acc_k16(const float* __restrict__ W, int rowOff, int K,
                                        const float x[][LDW], int j, float* acc) {
  for (int k4 = 0; k4 < K; k4 += 4) {
    float4 xa[RROWS];
    #pragma unroll
    for (int r = 0; r < RROWS; ++r) xa[r] = *(const float4*)&x[r][k4];
    #pragma unroll
    for (int kk = 0; kk < 4; ++kk) {
      float w = W[(size_t)(rowOff + k4 + kk) * 256 + j];
      #pragma unroll
      for (int r = 0; r < RROWS; ++r) {
        float xv = kk == 0 ? xa[r].x : kk == 1 ? xa[r].y : kk == 2 ? xa[r].z : xa[r].w;
        acc[r] = fmaf(xv, w, acc[r]);
      }
    }
  }
}

__global__ __launch_bounds__(256) void GeRN_static(
    const float* __restrict__ cnd, const float* __restrict__ qj,
    const float* __restrict__ qd, const float* __restrict__ qv,
    const float* __restrict__ Wij, const float* __restrict__ bij,
    const float* __restrict__ Wid, const float* __restrict__ bid,
    const float* __restrict__ Wgj, const float* __restrict__ bgj,
    const float* __restrict__ Wgd, const float* __restrict__ bgd,
    float* __restrict__ ws, int B)
{
  __shared__ float sx[RROWS][256];
  __shared__ float sqj[RROWS][64];
  __shared__ float sqd[RROWS][64];
  __shared__ float sqv[RROWS][4];
  const int tid = threadIdx.x;
  const int b0 = blockIdx.x * RROWS;
  for (int i = tid; i < RROWS * 256; i += 256) {
    int r = i >> 8, c = i & 255;
    sx[r][c] = cnd[(size_t)(b0 + r) * 256 + c];
  }
  for (int i = tid; i < RROWS * 64; i += 256) {
    int r = i >> 6, c = i & 63;
    sqj[r][c] = qj[(size_t)(b0 + r) * 64 + c];
    sqd[r][c] = qd[(size_t)(b0 + r) * 64 + c];
  }
  if (tid < RROWS * 4) {
    int r = tid >> 2, c = tid & 3;
    sqv[r][c] = qv[(size_t)(b0 + r) * 4 + c];
  }
  __syncthreads();
  const int j = tid; // output column 0..255
  float* pre_ij = ws;
  float* pre_id = ws + (size_t)B * 256;
  float* pre_gj = ws + (size_t)2 * B * 256;
  float* pre_gd = ws + (size_t)3 * B * 256;
  float acc[RROWS];

  { // pre_ij: cnd rows 0..255, qry_jrep rows 256..319
    float bb = bij[j];
    #pragma unroll
    for (int r = 0; r < RROWS; ++r) acc[r] = bb;
    acc_k16<256>(Wij, 0, 256, sx, j, acc);
    acc_k16<64>(Wij, 256, 64, sqj, j, acc);
    #pragma unroll
    for (int r = 0; r < RROWS; ++r) pre_ij[(size_t)(b0 + r) * 256 + j] = acc[r];
  }
  { // pre_id: cnd + qry_drep
    float bb = bid[j];
    #pragma unroll
    for (int r = 0; r < RROWS; ++r) acc[r] = bb;
    acc_k16<256>(Wid, 0, 256, sx, j, acc);
    acc_k16<64>(Wid, 256, 64, sqd, j, acc);
    #pragma unroll
    for (int r = 0; r < RROWS; ++r) pre_id[(size_t)(b0 + r) * 256 + j] = acc[r];
  }
  { // pre_gj: cnd only
    float bb = bgj[j];
    #pragma unroll
    for (int r = 0; r < RROWS; ++r) acc[r] = bb;
    acc_k16<256>(Wgj, 0, 256, sx, j, acc);
    #pragma unroll
    for (int r = 0; r < RROWS; ++r) pre_gj[(size_t)(b0 + r) * 256 + j] = acc[r];
  }
  { // pre_gd: cnd rows 0..255 + qry_v rows 320..323
    float bb = bgd[j];
    #pragma unroll
    for (int r = 0; r < RROWS; ++r) acc[r] = bb;
    acc_k16<256>(Wgd, 0, 256, sx, j, acc);
    for (int k = 0; k < 4; ++k) {
      float w = Wgd[(size_t)(320 + k) * 256 + j];
      #pragma unroll
      for (int r = 0; r < RROWS; ++r) acc[r] = fmaf(sqv[r][k], w, acc[r]);
    }
    #pragma unroll
    for (int r = 0; r < RROWS; ++r) pre_gd[(size_t)(b0 + r) * 256 + j] = acc[r];
  }
}

// ================= Kernel 2: fused 12-step recurrence =================
// thread t: h = t&63 (hidden unit), rg = t>>6; owns rows rg*NROW..rg*NROW+3.
// Each wave exclusively owns its 4 state rows (rows never cross waves).

__device__ __forceinline__ void lstm_block(
    const float* __restrict__ W, int row1, int row2,
    const float* __restrict__ pre,
    const float (*x1)[64], float (*x2)[64],
    float* c, float zo, int bbase, int r0, int h)
{
  float ai[NROW], af[NROW], ag[NROW], ao[NROW];
  #pragma unroll
  for (int rr = 0; rr < NROW; ++rr) {
    const float* p = pre + (size_t)(bbase + r0 + rr) * 256 + h;
    ai[rr] = p[0]; af[rr] = p[64]; ag[rr] = p[128]; ao[rr] = p[192];
  }
  for (int k4 = 0; k4 < 64; k4 += 4) { // x1 block
    float4 xa[NROW];
    #pragma unroll
    for (int rr = 0; rr < NROW; ++rr) xa[rr] = *(const float4*)&x1[r0 + rr][k4];
    #pragma unroll
    for (int kk = 0; kk < 4; ++kk) {
      const float* wr = W + (size_t)(row1 + k4 + kk) * 256 + h;
      float wi = wr[0], wf = wr[64], wg = wr[128], wo = wr[192];
      #pragma unroll
      for (int rr = 0; rr < NROW; ++rr) {
        float xv = kk == 0 ? xa[rr].x : kk == 1 ? xa[rr].y : kk == 2 ? xa[rr].z : xa[rr].w;
        ai[rr] = fmaf(xv, wi, ai[rr]); af[rr] = fmaf(xv, wf, af[rr]);
        ag[rr] = fmaf(xv, wg, ag[rr]); ao[rr] = fmaf(xv, wo, ao[rr]);
      }
    }
  }
  for (int k4 = 0; k4 < 64; k4 += 4) { // x2 (own h-state) block
    float4 xa[NROW];
    #pragma unroll
    for (int rr = 0; rr < NROW; ++rr) xa[rr] = *(const float4*)&x2[r0 + rr][k4];
    #pragma unroll
    for (int kk = 0; kk < 4; ++kk) {
      const float* wr = W + (size_t)(row2 + k4 + kk) * 256 + h;
      float wi = wr[0], wf = wr[64], wg = wr[128], wo = wr[192];
      #pragma unroll
      for (int rr = 0; rr < NROW; ++rr) {
        float xv = kk == 0 ? xa[rr].x : kk == 1 ? xa[rr].y : kk == 2 ? xa[rr].z : xa[rr].w;
        ai[rr] = fmaf(xv, wi, ai[rr]); af[rr] = fmaf(xv, wf, af[rr]);
        ag[rr] = fmaf(xv, wg, ag[rr]); ao[rr] = fmaf(xv, wo, ao[rr]);
      }
    }
  }
  const float zo1 = 1.0f - zo;
  #pragma unroll
  for (int rr = 0; rr < NROW; ++rr) {
    float ig = sigmoidf_(ai[rr]);
    float fg = sigmoidf_(af[rr]);
    float gg = tanhf(ag[rr]);
    float og = sigmoidf_(ao[rr]);
    float cn = fmaf(fg, c[rr], ig * gg);
    float hn = og * tanhf(cn);
    float hold = x2[r0 + rr][h];               // own lane's column: no race
    x2[r0 + rr][h] = fmaf(zo, hold, zo1 * hn); // zoneout blend
    c[rr] = fmaf(zo, c[rr], zo1 * cn);
  }
}

__device__ __forceinline__ void head2(
    const float* __restrict__ W, const float* __restrict__ bv,
    const float (*x)[64], int r0, int h, float* m, float* v)
{
  float bm = bv[h], blv = bv[64 + h];
  #pragma unroll
  for (int rr = 0; rr < NROW; ++rr) { m[rr] = bm; v[rr] = blv; }
  for (int k4 = 0; k4 < 64; k4 += 4) {
    float4 xa[NROW];
    #pragma unroll
    for (int rr = 0; rr < NROW; ++rr) xa[rr] = *(const float4*)&x[r0 + rr][k4];
    #pragma unroll
    for (int kk = 0; kk < 4; ++kk) {
      const float* wr = W + (size_t)(k4 + kk) * 128 + h;
      float wm = wr[0], wv = wr[64];
      #pragma unroll
      for (int rr = 0; rr < NROW; ++rr) {
        float xv = kk == 0 ? xa[rr].x : kk == 1 ? xa[rr].y : kk == 2 ? xa[rr].z : xa[rr].w;
        m[rr] = fmaf(xv, wm, m[rr]); v[rr] = fmaf(xv, wv, v[rr]);
      }
    }
  }
}

__device__ __forceinline__ void delta_upd(
    const float* __restrict__ W, const float* __restrict__ bv,
    float (*u)[64], const float (*hg)[64], int r0, int h)
{
  float a[NROW];
  float bb = bv[h];
  #pragma unroll
  for (int rr = 0; rr < NROW; ++rr) a[rr] = bb;
  for (int k4 = 0; k4 < 64; k4 += 4) {
    float4 xa[NROW], xb[NROW];
    #pragma unroll
    for (int rr = 0; rr < NROW; ++rr) {
      xa[rr] = *(const float4*)&u[r0 + rr][k4];
      xb[rr] = *(const float4*)&hg[r0 + rr][k4];
    }
    #pragma unroll
    for (int kk = 0; kk < 4; ++kk) {
      float wu = W[(size_t)(k4 + kk) * 64 + h];
      float wh = W[(size_t)(64 + k4 + kk) * 64 + h];
      #pragma unroll
      for (int rr = 0; rr < NROW; ++rr) {
        float xua = kk == 0 ? xa[rr].x : kk == 1 ? xa[rr].y : kk == 2 ? xa[rr].z : xa[rr].w;
        float xhb = kk == 0 ? xb[rr].x : kk == 1 ? xb[rr].y : kk == 2 ? xb[rr].z : xb[rr].w;
        a[rr] = fmaf(xua, wu, a[rr]);
        a[rr] = fmaf(xhb, wh, a[rr]);
      }
    }
  }
  #pragma unroll
  for (int rr = 0; rr < NROW; ++rr) {
    float d = a[rr] > 0.0f ? a[rr] : 0.01f * a[rr]; // leaky_relu(0.01)
    u[r0 + rr][h] += d;
  }
}

__global__ __launch_bounds__(256) void GeRN_recur(
    const float* __restrict__ Wij, const float* __restrict__ Wid,
    const float* __restrict__ Wgj, const float* __restrict__ Wgd,
    const float* __restrict__ Wpoj, const float* __restrict__ bpoj,
    const float* __restrict__ Wpod, const float* __restrict__ bpod,
    const float* __restrict__ Wprj, const float* __restrict__ bprj,
    const float* __restrict__ Wprd, const float* __restrict__ bprd,
    const float* __restrict__ Wdj, const float* __restrict__ bdj,
    const float* __restrict__ Wdd, const float* __restrict__ bdd,
    const float* __restrict__ hi_j0, const float* __restrict__ ci_j0,
    const float* __restrict__ hi_d0, const float* __restrict__ ci_d0,
    const float* __restrict__ hg_j0, const float* __restrict__ cg_j0,
    const float* __restrict__ hg_d0, const float* __restrict__ cg_d0,
    const float* __restrict__ ug_j0, const float* __restrict__ ug_d0,
    const float* __restrict__ ws, float* __restrict__ out,
    int B, int nd)
{
  __shared__ float sh_hi_j[RROWS][64], sh_hi_d[RROWS][64];
  __shared__ float sh_hg_j[RROWS][64], sh_hg_d[RROWS][64];
  __shared__ float sh_zj[RROWS][64], sh_zd[RROWS][64];
  __shared__ float sh_uj[RROWS][64], sh_ud[RROWS][64];

  const int tid = threadIdx.x;
  const int h = tid & 63;
  const int r0 = (tid >> 6) * NROW;
  const int bbase = blockIdx.x * RROWS;
  const size_t BN = (size_t)B * 64;
  const float* pre_ij = ws;
  const float* pre_id = ws + (size_t)B * 256;
  const float* pre_gj = ws + (size_t)2 * B * 256;
  const float* pre_gd = ws + (size_t)3 * B * 256;

  float c_ij[NROW], c_id[NROW], c_gj[NROW], c_gd[NROW];
  #pragma unroll
  for (int rr = 0; rr < NROW; ++rr) {
    size_t gi = (size_t)(bbase + r0 + rr) * 64 + h;
    sh_hi_j[r0 + rr][h] = hi_j0[gi]; c_ij[rr] = ci_j0[gi];
    sh_hi_d[r0 + rr][h] = hi_d0[gi]; c_id[rr] = ci_d0[gi];
    sh_hg_j[r0 + rr][h] = hg_j0[gi]; c_gj[rr] = cg_j0[gi];
    sh_hg_d[r0 + rr][h] = hg_d0[gi]; c_gd[rr] = cg_d0[gi];
    sh_uj[r0 + rr][h] = ug_j0[gi];
    sh_ud[r0 + rr][h] = ug_d0[gi];
  }
  __syncthreads();

  for (int t = 0; t < nd; ++t) {
    float m[NROW], v[NROW];
    // ---- priors from current hg (pre-update) ----
    head2(Wprj, bprj, sh_hg_j, r0, h, m, v);
    #pragma unroll
    for (int rr = 0; rr < NROW; ++rr) {
      size_t gi = (size_t)(bbase + r0 + rr) * 64 + h;
      out[(size_t)(2 + 0 * nd + t) * BN + gi] = m[rr];
      out[(size_t)(2 + 1 * nd + t) * BN + gi] = v[rr];
    }
    head2(Wprd, bprd, sh_hg_d, r0, h, m, v);
    #pragma unroll
    for (int rr = 0; rr < NROW; ++rr) {
      size_t gi = (size_t)(bbase + r0 + rr) * 64 + h;
      out[(size_t)(2 + 2 * nd + t) * BN + gi] = m[rr];
      out[(size_t)(2 + 3 * nd + t) * BN + gi] = v[rr];
    }
    // ---- inference LSTMs (x = [cnd,qry,hg], h = hi) ----
    lstm_block(Wij, 320, 384, pre_ij, sh_hg_j, sh_hi_j, c_ij, 0.3f, bbase, r0, h);
    lstm_block(Wid, 320, 384, pre_id, sh_hg_d, sh_hi_d, c_id, 0.2f, bbase, r0, h);
    __syncthreads();
    // ---- posteriors + reparameterized z ----
    head2(Wpoj, bpoj, sh_hi_j, r0, h, m, v);
    #pragma unroll
    for (int rr = 0; rr < NROW; ++rr) {
      size_t gi = (size_t)(bbase + r0 + rr) * 64 + h;
      out[(size_t)(2 + 4 * nd + t) * BN + gi] = m[rr];
      out[(size_t)(2 + 5 * nd + t) * BN + gi] = v[rr];
      unsigned idx = (unsigned)((size_t)t * BN + gi);
      float e = eps_threefry(1u, idx);
      sh_zj[r0 + rr][h] = fmaf(expf(0.5f * v[rr]), e, m[rr]);
    }
    head2(Wpod, bpod, sh_hi_d, r0, h, m, v);
    #pragma unroll
    for (int rr = 0; rr < NROW; ++rr) {
      size_t gi = (size_t)(bbase + r0 + rr) * 64 + h;
      out[(size_t)(2 + 6 * nd + t) * BN + gi] = m[rr];
      out[(size_t)(2 + 7 * nd + t) * BN + gi] = v[rr];
      unsigned idx = (unsigned)((size_t)t * BN + gi);
      float e = eps_threefry(2u, idx);
      sh_zd[r0 + rr][h] = fmaf(expf(0.5f * v[rr]), e, m[rr]);
    }
    __syncthreads();
    // ---- generator LSTMs (x = [cnd, z(, qv)], h = hg) ----
    lstm_block(Wgj, 256, 320, pre_gj, sh_zj, sh_hg_j, c_gj, 0.3f, bbase, r0, h);
    lstm_block(Wgd, 256, 324, pre_gd, sh_zd, sh_hg_d, c_gd, 0.2f, bbase, r0, h);
    __syncthreads();
    // ---- additive canvas deltas ----
    delta_upd(Wdj, bdj, sh_uj, sh_hg_j, r0, h);
    delta_upd(Wdd, bdd, sh_ud, sh_hg_d, r0, h);
    __syncthreads();
  }
  // ---- final canvases ----
  #pragma unroll
  for (int rr = 0; rr < NROW; ++rr) {
    size_t gi = (size_t)(bbase + r0 + rr) * 64 + h;
    out[gi] = sh_uj[r0 + rr][h];
    out[BN + gi] = sh_ud[r0 + rr][h];
  }
}

extern "C" void kernel_launch(void* const* d_in, const int* in_sizes, int n_in,
                              void* d_out, int out_size, void* d_ws, size_t ws_size,
                              hipStream_t stream)
{
  const float* cnd = (const float*)d_in[1];
  const float* qj  = (const float*)d_in[2];
  const float* qd  = (const float*)d_in[3];
  const float* qv  = (const float*)d_in[4];
  const float* hi_j0 = (const float*)d_in[5];
  const float* ci_j0 = (const float*)d_in[6];
  const float* hi_d0 = (const float*)d_in[8];
  const float* ci_d0 = (const float*)d_in[9];
  const float* hg_j0 = (const float*)d_in[11];
  const float* cg_j0 = (const float*)d_in[12];
  const float* hg_d0 = (const float*)d_in[14];
  const float* cg_d0 = (const float*)d_in[15];
  const float* ug_j0 = (const float*)d_in[17];
  const float* ug_d0 = (const float*)d_in[18];
  const float* Wij = (const float*)d_in[19]; const float* bij = (const float*)d_in[20];
  const float* Wid = (const float*)d_in[21]; const float* bid = (const float*)d_in[22];
  const float* Wgj = (const float*)d_in[23]; const float* bgj = (const float*)d_in[24];
  const float* Wgd = (const float*)d_in[25]; const float* bgd = (const float*)d_in[26];
  const float* Wpoj = (const float*)d_in[27]; const float* bpoj = (const float*)d_in[28];
  const float* Wpod = (const float*)d_in[29]; const float* bpod = (const float*)d_in[30];
  const float* Wprj = (const float*)d_in[31]; const float* bprj = (const float*)d_in[32];
  const float* Wprd = (const float*)d_in[33]; const float* bprd = (const float*)d_in[34];
  const float* Wdj = (const float*)d_in[35]; const float* bdj = (const float*)d_in[36];
  const float* Wdd = (const float*)d_in[37]; const float* bdd = (const float*)d_in[38];

  const int B = in_sizes[1] / 256;                 // cnd_repr is [B,256]
  const int slots = out_size / (B * 64);           // 2 + 8*ndraw
  const int nd = (slots - 2) / 8;

  float* ws = (float*)d_ws;   // 4 * B * 256 f32 = 32 MB at B=8192
  float* out = (float*)d_out;

  GeRN_static<<<B / RROWS, 256, 0, stream>>>(
      cnd, qj, qd, qv, Wij, bij, Wid, bid, Wgj, bgj, Wgd, bgd, ws, B);
  GeRN_recur<<<B / RROWS, 256, 0, stream>>>(
      Wij, Wid, Wgj, Wgd, Wpoj, bpoj, Wpod, bpod, Wprj, bprj, Wprd, bprd,
      Wdj, bdj, Wdd, bdd,
      hi_j0, ci_j0, hi_d0, ci_d0, hg_j0, cg_j0, hg_d0, cg_d0, ug_j0, ug_d0,
      ws, out, B, nd);
}

// Round 3
// 1116.929 us; speedup vs baseline: 55.9728x; 55.9728x over previous
//
#include <hip/hip_runtime.h>
#include <hip/hip_bf16.h>

// GeRN fused, round 3: register-light recurrence.
// kernel1 (unchanged): precompute static (cnd/qry/qv + bias) gate pre-acts.
// kernel2: 512 threads/block, 16 batch rows/block.
//   matmul role:  grp = tid>>8 (0=j,1=d), mc = tid&255 (gate column) —
//                 each thread accumulates all 16 rows for one column.
//   state role:   h = tid&63, rr = tid>>6 (owns rows rr, rr+8 for both j,d).
// States in LDS; gates through a 32KB LDS scratch; static pre-acts in VGPRs;
// out stores nontemporal (protect weight set in L2).

#define NROW 4      // static kernel rows per thread-group
#define RROWS 16    // rows per block (both kernels)
#define R16 16

__device__ __forceinline__ float sigf(float x) {
  return 1.0f / (1.0f + __expf(-x));
}
__device__ __forceinline__ float tanh_f(float x) {
  return 1.0f - 2.0f / (__expf(2.0f * x) + 1.0f);
}

// --- JAX threefry2x32-20 (partitionable) + uniform + XLA ErfInv32 (Giles) ---
__device__ __forceinline__ float eps_threefry(unsigned seed, unsigned idx) {
  unsigned x0 = 0u, x1 = idx;
  const unsigned ks0 = 0u, ks1 = seed, ks2 = seed ^ 0x1BD11BDAu;
  x0 += ks0; x1 += ks1;
#define TF_R(r) { x0 += x1; x1 = (x1 << (r)) | (x1 >> (32 - (r))); x1 ^= x0; }
  TF_R(13) TF_R(15) TF_R(26) TF_R(6)  x0 += ks1; x1 += ks2 + 1u;
  TF_R(17) TF_R(29) TF_R(16) TF_R(24) x0 += ks2; x1 += ks0 + 2u;
  TF_R(13) TF_R(15) TF_R(26) TF_R(6)  x0 += ks0; x1 += ks1 + 3u;
  TF_R(17) TF_R(29) TF_R(16) TF_R(24) x0 += ks1; x1 += ks2 + 4u;
  TF_R(13) TF_R(15) TF_R(26) TF_R(6)  x0 += ks2; x1 += ks0 + 5u;
#undef TF_R
  unsigned bits = x0 ^ x1;
  unsigned fb = (bits >> 9) | 0x3F800000u;
  const float lo = -0.99999994f;
  float f = __uint_as_float(fb) - 1.0f;
  float u = fmaxf(lo, f * 2.0f + lo);
  float w = -log1pf(-u * u);
  float p;
  if (w < 5.0f) {
    w -= 2.5f;
    p = 2.81022636e-08f;
    p = fmaf(p, w, 3.43273939e-07f);
    p = fmaf(p, w, -3.5233877e-06f);
    p = fmaf(p, w, -4.39150654e-06f);
    p = fmaf(p, w, 0.00021858087f);
    p = fmaf(p, w, -0.00125372503f);
    p = fmaf(p, w, -0.00417768164f);
    p = fmaf(p, w, 0.246640727f);
    p = fmaf(p, w, 1.50140941f);
  } else {
    w = sqrtf(w) - 3.0f;
    p = -0.000200214257f;
    p = fmaf(p, w, 0.000100950558f);
    p = fmaf(p, w, 0.00134934322f);
    p = fmaf(p, w, -0.00367342844f);
    p = fmaf(p, w, 0.00573950773f);
    p = fmaf(p, w, -0.0076224613f);
    p = fmaf(p, w, 0.00943887047f);
    p = fmaf(p, w, 1.00167406f);
    p = fmaf(p, w, 2.83297682f);
  }
  return 1.41421356f * (p * u);
}

// ================= Kernel 1: static precompute (unchanged, passing) ========
template<int LDW>
__device__ __forceinline__ void acc_k16(const float* __restrict__ W, int rowOff, int K,
                                        const float x[][LDW], int j, float* acc) {
  for (int k4 = 0; k4 < K; k4 += 4) {
    float4 xa[RROWS];
    #pragma unroll
    for (int r = 0; r < RROWS; ++r) xa[r] = *(const float4*)&x[r][k4];
    #pragma unroll
    for (int kk = 0; kk < 4; ++kk) {
      float w = W[(size_t)(rowOff + k4 + kk) * 256 + j];
      #pragma unroll
      for (int r = 0; r < RROWS; ++r) {
        float xv = kk == 0 ? xa[r].x : kk == 1 ? xa[r].y : kk == 2 ? xa[r].z : xa[r].w;
        acc[r] = fmaf(xv, w, acc[r]);
      }
    }
  }
}

__global__ __launch_bounds__(256) void GeRN_static(
    const float* __restrict__ cnd, const float* __restrict__ qj,
    const float* __restrict__ qd, const float* __restrict__ qv,
    const float* __restrict__ Wij, const float* __restrict__ bij,
    const float* __restrict__ Wid, const float* __restrict__ bid,
    const float* __restrict__ Wgj, const float* __restrict__ bgj,
    const float* __restrict__ Wgd, const float* __restrict__ bgd,
    float* __restrict__ ws, int B)
{
  __shared__ float sx[RROWS][256];
  __shared__ float sqj[RROWS][64];
  __shared__ float sqd[RROWS][64];
  __shared__ float sqv[RROWS][4];
  const int tid = threadIdx.x;
  const int b0 = blockIdx.x * RROWS;
  for (int i = tid; i < RROWS * 256; i += 256) {
    int r = i >> 8, c = i & 255;
    sx[r][c] = cnd[(size_t)(b0 + r) * 256 + c];
  }
  for (int i = tid; i < RROWS * 64; i += 256) {
    int r = i >> 6, c = i & 63;
    sqj[r][c] = qj[(size_t)(b0 + r) * 64 + c];
    sqd[r][c] = qd[(size_t)(b0 + r) * 64 + c];
  }
  if (tid < RROWS * 4) {
    int r = tid >> 2, c = tid & 3;
    sqv[r][c] = qv[(size_t)(b0 + r) * 4 + c];
  }
  __syncthreads();
  const int j = tid;
  float* pre_ij = ws;
  float* pre_id = ws + (size_t)B * 256;
  float* pre_gj = ws + (size_t)2 * B * 256;
  float* pre_gd = ws + (size_t)3 * B * 256;
  float acc[RROWS];

  {
    float bb = bij[j];
    #pragma unroll
    for (int r = 0; r < RROWS; ++r) acc[r] = bb;
    acc_k16<256>(Wij, 0, 256, sx, j, acc);
    acc_k16<64>(Wij, 256, 64, sqj, j, acc);
    #pragma unroll
    for (int r = 0; r < RROWS; ++r) pre_ij[(size_t)(b0 + r) * 256 + j] = acc[r];
  }
  {
    float bb = bid[j];
    #pragma unroll
    for (int r = 0; r < RROWS; ++r) acc[r] = bb;
    acc_k16<256>(Wid, 0, 256, sx, j, acc);
    acc_k16<64>(Wid, 256, 64, sqd, j, acc);
    #pragma unroll
    for (int r = 0; r < RROWS; ++r) pre_id[(size_t)(b0 + r) * 256 + j] = acc[r];
  }
  {
    float bb = bgj[j];
    #pragma unroll
    for (int r = 0; r < RROWS; ++r) acc[r] = bb;
    acc_k16<256>(Wgj, 0, 256, sx, j, acc);
    #pragma unroll
    for (int r = 0; r < RROWS; ++r) pre_gj[(size_t)(b0 + r) * 256 + j] = acc[r];
  }
  {
    float bb = bgd[j];
    #pragma unroll
    for (int r = 0; r < RROWS; ++r) acc[r] = bb;
    acc_k16<256>(Wgd, 0, 256, sx, j, acc);
    for (int k = 0; k < 4; ++k) {
      float w = Wgd[(size_t)(320 + k) * 256 + j];
      #pragma unroll
      for (int r = 0; r < RROWS; ++r) acc[r] = fmaf(sqv[r][k], w, acc[r]);
    }
    #pragma unroll
    for (int r = 0; r < RROWS; ++r) pre_gd[(size_t)(b0 + r) * 256 + j] = acc[r];
  }
}

// ================= Kernel 2: fused 12-step recurrence (v2) =================

// LSTM gate matmul: thread (grp, mc) computes gate[r][mc] for r=0..15.
// acc init from register-resident pre; two 64-k halves from LDS states.
#define MM_LSTM_HALF(WB, XP) \
    for (int k4 = 0; k4 < 64; k4 += 4) { \
      float w0 = (WB)[(size_t)(k4 + 0) * 256]; \
      float w1 = (WB)[(size_t)(k4 + 1) * 256]; \
      float w2 = (WB)[(size_t)(k4 + 2) * 256]; \
      float w3 = (WB)[(size_t)(k4 + 3) * 256]; \
      _Pragma("unroll") \
      for (int r = 0; r < R16; ++r) { \
        float4 xv = *(const float4*)((XP) + r * 64 + k4); \
        acc[r] = fmaf(xv.x, w0, acc[r]); \
        acc[r] = fmaf(xv.y, w1, acc[r]); \
        acc[r] = fmaf(xv.z, w2, acc[r]); \
        acc[r] = fmaf(xv.w, w3, acc[r]); \
      } \
    }

#define MM_LSTM(WP, ROW1, X1, ROW2, X2, PRE) do { \
    float acc[R16]; \
    _Pragma("unroll") \
    for (int r = 0; r < R16; ++r) acc[r] = (PRE)[r]; \
    { const float* Wb = (WP) + (size_t)(ROW1) * 256 + mc; MM_LSTM_HALF(Wb, X1) } \
    { const float* Wb = (WP) + (size_t)(ROW2) * 256 + mc; MM_LSTM_HALF(Wb, X2) } \
    _Pragma("unroll") \
    for (int r = 0; r < R16; ++r) gbuf[(grp * R16 + r) * 256 + mc] = acc[r]; \
  } while (0)

// Gate nonlinearity + zoneout. Thread handles (jd, rows rr & rr+8) at unit h.
#define NONLIN(SIDX, CST, ZOJ, ZOD) do { \
    _Pragma("unroll") \
    for (int jd = 0; jd < 2; ++jd) { \
      const float zo = jd ? (ZOD) : (ZOJ); \
      const float zo1 = 1.0f - zo; \
      _Pragma("unroll") \
      for (int p = 0; p < 2; ++p) { \
        int rl = rr + p * 8; \
        float gi_ = sigf(gbuf[(jd * R16 + rl) * 256 + h]); \
        float gf_ = sigf(gbuf[(jd * R16 + rl) * 256 + 64 + h]); \
        float gg_ = tanh_f(gbuf[(jd * R16 + rl) * 256 + 128 + h]); \
        float go_ = sigf(gbuf[(jd * R16 + rl) * 256 + 192 + h]); \
        float cn = fmaf(gf_, CST[jd][p], gi_ * gg_); \
        float hn = go_ * tanh_f(cn); \
        float hold = st[(SIDX) + jd][rl][h]; \
        st[(SIDX) + jd][rl][h] = fmaf(zo, hold, zo1 * hn); \
        CST[jd][p] = fmaf(zo, CST[jd][p], zo1 * cn); \
      } \
    } \
  } while (0)

// Head matmul (64k -> 128 cols m|logv). Roles: hd=grp, c2=mc&127, kh=mc>>7.
// Result (with bias) lands in gbuf slot ((hd*2)*16 + r)*128 + c2.
#define MM_HEAD(WH, BH, XS) do { \
    float acc[R16]; \
    _Pragma("unroll") \
    for (int r = 0; r < R16; ++r) acc[r] = 0.0f; \
    { const float* Wb = (WH) + (size_t)(kh * 32) * 128 + c2; \
      const float* xb = (XS) + kh * 32; \
      for (int k4 = 0; k4 < 32; k4 += 4) { \
        float w0 = Wb[(size_t)(k4 + 0) * 128]; \
        float w1 = Wb[(size_t)(k4 + 1) * 128]; \
        float w2 = Wb[(size_t)(k4 + 2) * 128]; \
        float w3 = Wb[(size_t)(k4 + 3) * 128]; \
        _Pragma("unroll") \
        for (int r = 0; r < R16; ++r) { \
          float4 xv = *(const float4*)(xb + r * 64 + k4); \
          acc[r] = fmaf(xv.x, w0, acc[r]); \
          acc[r] = fmaf(xv.y, w1, acc[r]); \
          acc[r] = fmaf(xv.z, w2, acc[r]); \
          acc[r] = fmaf(xv.w, w3, acc[r]); \
        } \
      } } \
    if (kh) { \
      _Pragma("unroll") \
      for (int r = 0; r < R16; ++r) gbuf[((grp * 2 + 1) * R16 + r) * 128 + c2] = acc[r]; \
    } \
    __syncthreads(); \
    if (!kh) { \
      float bb = (BH)[c2]; \
      _Pragma("unroll") \
      for (int r = 0; r < R16; ++r) \
        gbuf[((grp * 2) * R16 + r) * 128 + c2] = \
            acc[r] + gbuf[((grp * 2 + 1) * R16 + r) * 128 + c2] + bb; \
    } \
    __syncthreads(); \
  } while (0)

__global__ __launch_bounds__(512, 4) void GeRN_recur(
    const float* __restrict__ Wij, const float* __restrict__ Wid,
    const float* __restrict__ Wgj, const float* __restrict__ Wgd,
    const float* __restrict__ Wpoj, const float* __restrict__ bpoj,
    const float* __restrict__ Wpod, const float* __restrict__ bpod,
    const float* __restrict__ Wprj, const float* __restrict__ bprj,
    const float* __restrict__ Wprd, const float* __restrict__ bprd,
    const float* __restrict__ Wdj, const float* __restrict__ bdj,
    const float* __restrict__ Wdd, const float* __restrict__ bdd,
    const float* __restrict__ hi_j0, const float* __restrict__ ci_j0,
    const float* __restrict__ hi_d0, const float* __restrict__ ci_d0,
    const float* __restrict__ hg_j0, const float* __restrict__ cg_j0,
    const float* __restrict__ hg_d0, const float* __restrict__ cg_d0,
    const float* __restrict__ ug_j0, const float* __restrict__ ug_d0,
    const float* __restrict__ ws, float* __restrict__ out,
    int B, int nd)
{
  // st: 0:hi_j 1:hi_d 2:hg_j 3:hg_d 4:z_j 5:z_d 6:u_j 7:u_d   (32 KB)
  __shared__ float st[8][R16][64];
  __shared__ float gbuf[8192];          // 32 KB phase scratch

  const int tid = threadIdx.x;
  const int bbase = blockIdx.x * R16;
  const size_t BN = (size_t)B * 64;
  // matmul role
  const int grp = tid >> 8;             // 0 = j-side, 1 = d-side (wave-uniform)
  const int mc  = tid & 255;            // gate column
  const int c2  = mc & 127;             // head column
  const int kh  = mc >> 7;              // head k-half (wave-uniform)
  // state role
  const int h  = tid & 63;
  const int rr = tid >> 6;              // rows rr, rr+8  (rr in 0..7)

  const float* pre_ij = ws;
  const float* pre_id = ws + (size_t)B * 256;
  const float* pre_gj = ws + (size_t)2 * B * 256;
  const float* pre_gd = ws + (size_t)3 * B * 256;

  // ---- load states into LDS ----
  for (int i = tid; i < R16 * 64; i += 512) {
    int r = i >> 6, hh = i & 63;
    size_t gi = (size_t)(bbase + r) * 64 + hh;
    st[0][r][hh] = hi_j0[gi]; st[1][r][hh] = hi_d0[gi];
    st[2][r][hh] = hg_j0[gi]; st[3][r][hh] = hg_d0[gi];
    st[6][r][hh] = ug_j0[gi]; st[7][r][hh] = ug_d0[gi];
  }
  // cell states in registers (state role)
  float cI[2][2], cG[2][2];
  {
    size_t g0 = (size_t)(bbase + rr) * 64 + h;
    size_t g1 = (size_t)(bbase + rr + 8) * 64 + h;
    cI[0][0] = ci_j0[g0]; cI[0][1] = ci_j0[g1];
    cI[1][0] = ci_d0[g0]; cI[1][1] = ci_d0[g1];
    cG[0][0] = cg_j0[g0]; cG[0][1] = cg_j0[g1];
    cG[1][0] = cg_d0[g0]; cG[1][1] = cg_d0[g1];
  }
  // static pre-activations resident in registers (matmul role)
  float preI[R16], preG[R16];
  {
    const float* pI = (grp ? pre_id : pre_ij) + (size_t)bbase * 256 + mc;
    const float* pG = (grp ? pre_gd : pre_gj) + (size_t)bbase * 256 + mc;
    #pragma unroll
    for (int r = 0; r < R16; ++r) {
      preI[r] = pI[(size_t)r * 256];
      preG[r] = pG[(size_t)r * 256];
    }
  }
  __syncthreads();

  const float* WI  = grp ? Wid : Wij;
  const float* WG  = grp ? Wgd : Wgj;
  const int row2g  = grp ? 324 : 320;
  const float* WPR = grp ? Wprd : Wprj;  const float* BPR = grp ? bprd : bprj;
  const float* WPO = grp ? Wpod : Wpoj;  const float* BPO = grp ? bpod : bpoj;
  const float* WD  = grp ? Wdd : Wdj;    const float* BD  = grp ? bdd : bdj;
  // delta roles
  const int dc = mc & 63;                // delta column
  const int kq = mc >> 6;                // delta k-quarter (wave-uniform)

  for (int t = 0; t < nd; ++t) {
    // ======== priors from current hg ========
    MM_HEAD(WPR, BPR, &st[2 + grp][0][0]);
    #pragma unroll
    for (int hd = 0; hd < 2; ++hd) {
      #pragma unroll
      for (int p = 0; p < 2; ++p) {
        int rl = rr + p * 8;
        float m = gbuf[((hd * 2) * R16 + rl) * 128 + h];
        float v = gbuf[((hd * 2) * R16 + rl) * 128 + 64 + h];
        size_t gi = (size_t)(bbase + rl) * 64 + h;
        __builtin_nontemporal_store(m, out + (size_t)(2 + (hd * 2 + 0) * nd + t) * BN + gi);
        __builtin_nontemporal_store(v, out + (size_t)(2 + (hd * 2 + 1) * nd + t) * BN + gi);
      }
    }
    __syncthreads();
    // ======== inference LSTMs: x1=hg, x2=hi ========
    MM_LSTM(WI, 320, &st[2 + grp][0][0], 384, &st[0 + grp][0][0], preI);
    __syncthreads();
    NONLIN(0, cI, 0.3f, 0.2f);
    __syncthreads();
    // ======== posteriors from hi + z sample ========
    MM_HEAD(WPO, BPO, &st[0 + grp][0][0]);
    #pragma unroll
    for (int hd = 0; hd < 2; ++hd) {
      #pragma unroll
      for (int p = 0; p < 2; ++p) {
        int rl = rr + p * 8;
        float m = gbuf[((hd * 2) * R16 + rl) * 128 + h];
        float v = gbuf[((hd * 2) * R16 + rl) * 128 + 64 + h];
        size_t gi = (size_t)(bbase + rl) * 64 + h;
        __builtin_nontemporal_store(m, out + (size_t)(2 + (4 + hd * 2) * nd + t) * BN + gi);
        __builtin_nontemporal_store(v, out + (size_t)(2 + (5 + hd * 2) * nd + t) * BN + gi);
        unsigned idx = (unsigned)((size_t)t * BN + gi);
        float e = eps_threefry(1u + (unsigned)hd, idx);
        st[4 + hd][rl][h] = fmaf(__expf(0.5f * v), e, m);
      }
    }
    __syncthreads();
    // ======== generator LSTMs: x1=z, x2=hg ========
    MM_LSTM(WG, 256, &st[4 + grp][0][0], row2g, &st[2 + grp][0][0], preG);
    __syncthreads();
    NONLIN(2, cG, 0.3f, 0.2f);
    __syncthreads();
    // ======== canvas deltas: u += leaky(Wd @ [u, hg] + b) ========
    {
      const float* xs = (kq < 2) ? &st[6 + grp][0][0] : &st[2 + grp][0][0];
      const int koff = (kq & 1) * 32;
      float acc[R16];
      #pragma unroll
      for (int r = 0; r < R16; ++r) acc[r] = 0.0f;
      const float* Wb = WD + (size_t)(kq * 32) * 64 + dc;
      for (int k4 = 0; k4 < 32; k4 += 4) {
        float w0 = Wb[(size_t)(k4 + 0) * 64];
        float w1 = Wb[(size_t)(k4 + 1) * 64];
        float w2 = Wb[(size_t)(k4 + 2) * 64];
        float w3 = Wb[(size_t)(k4 + 3) * 64];
        #pragma unroll
        for (int r = 0; r < R16; ++r) {
          float4 xv = *(const float4*)(xs + r * 64 + koff + k4);
          acc[r] = fmaf(xv.x, w0, acc[r]);
          acc[r] = fmaf(xv.y, w1, acc[r]);
          acc[r] = fmaf(xv.z, w2, acc[r]);
          acc[r] = fmaf(xv.w, w3, acc[r]);
        }
      }
      if (kq) {
        #pragma unroll
        for (int r = 0; r < R16; ++r)
          gbuf[((grp * 4 + kq) * R16 + r) * 64 + dc] = acc[r];
      }
      __syncthreads();
      if (!kq) {
        float bb = BD[dc];
        #pragma unroll
        for (int r = 0; r < R16; ++r) {
          float a = acc[r] + bb
                  + gbuf[((grp * 4 + 1) * R16 + r) * 64 + dc]
                  + gbuf[((grp * 4 + 2) * R16 + r) * 64 + dc]
                  + gbuf[((grp * 4 + 3) * R16 + r) * 64 + dc];
          float d = a > 0.0f ? a : 0.01f * a;
          st[6 + grp][r][dc] += d;
        }
      }
      __syncthreads();
    }
  }

  // ---- final canvases ----
  #pragma unroll
  for (int p = 0; p < 2; ++p) {
    int rl = rr + p * 8;
    size_t gi = (size_t)(bbase + rl) * 64 + h;
    __builtin_nontemporal_store(st[6][rl][h], out + gi);
    __builtin_nontemporal_store(st[7][rl][h], out + BN + gi);
  }
}

extern "C" void kernel_launch(void* const* d_in, const int* in_sizes, int n_in,
                              void* d_out, int out_size, void* d_ws, size_t ws_size,
                              hipStream_t stream)
{
  const float* cnd = (const float*)d_in[1];
  const float* qj  = (const float*)d_in[2];
  const float* qd  = (const float*)d_in[3];
  const float* qv  = (const float*)d_in[4];
  const float* hi_j0 = (const float*)d_in[5];
  const float* ci_j0 = (const float*)d_in[6];
  const float* hi_d0 = (const float*)d_in[8];
  const float* ci_d0 = (const float*)d_in[9];
  const float* hg_j0 = (const float*)d_in[11];
  const float* cg_j0 = (const float*)d_in[12];
  const float* hg_d0 = (const float*)d_in[14];
  const float* cg_d0 = (const float*)d_in[15];
  const float* ug_j0 = (const float*)d_in[17];
  const float* ug_d0 = (const float*)d_in[18];
  const float* Wij = (const float*)d_in[19]; const float* bij = (const float*)d_in[20];
  const float* Wid = (const float*)d_in[21]; const float* bid = (const float*)d_in[22];
  const float* Wgj = (const float*)d_in[23]; const float* bgj = (const float*)d_in[24];
  const float* Wgd = (const float*)d_in[25]; const float* bgd = (const float*)d_in[26];
  const float* Wpoj = (const float*)d_in[27]; const float* bpoj = (const float*)d_in[28];
  const float* Wpod = (const float*)d_in[29]; const float* bpod = (const float*)d_in[30];
  const float* Wprj = (const float*)d_in[31]; const float* bprj = (const float*)d_in[32];
  const float* Wprd = (const float*)d_in[33]; const float* bprd = (const float*)d_in[34];
  const float* Wdj = (const float*)d_in[35]; const float* bdj = (const float*)d_in[36];
  const float* Wdd = (const float*)d_in[37]; const float* bdd = (const float*)d_in[38];

  const int B = in_sizes[1] / 256;                 // cnd_repr is [B,256]
  const int slots = out_size / (B * 64);           // 2 + 8*ndraw
  const int nd = (slots - 2) / 8;

  float* ws = (float*)d_ws;   // 4 * B * 256 f32 = 32 MB at B=8192
  float* out = (float*)d_out;

  GeRN_static<<<B / RROWS, 256, 0, stream>>>(
      cnd, qj, qd, qv, Wij, bij, Wid, bid, Wgj, bgj, Wgd, bgd, ws, B);
  GeRN_recur<<<B / R16, 512, 0, stream>>>(
      Wij, Wid, Wgj, Wgd, Wpoj, bpoj, Wpod, bpod, Wprj, bprj, Wprd, bprd,
      Wdj, bdj, Wdd, bdd,
      hi_j0, ci_j0, hi_d0, ci_d0, hg_j0, cg_j0, hg_d0, cg_d0, ug_j0, ug_d0,
      ws, out, B, nd);
}

// Round 4
// 626.970 us; speedup vs baseline: 99.7140x; 1.7815x over previous
//
#include <hip/hip_runtime.h>
#include <hip/hip_bf16.h>

// GeRN fused, round 4: MFMA recurrence.
//  kernel1 GeRN_static (f32, unchanged): static gate pre-activations -> ws.
//  kernel2 GeRN_prep: dynamic weight rows -> bf16 B-fragment layout in ws.
//  kernel3 GeRN_recur: 512 thr = 8 waves (waves 0-3 j-side, 4-7 d-side);
//    block owns 16 batch rows. All matmuls via mfma_f32_16x16x32_bf16.
//    Lane owns D-cells (row=(l>>4)*4+reg, col=ws*16+(l&15)); states f32 in
//    registers, mirrored to bf16 A-frag-layout LDS; pre in D-layout LDS.

#define RROWS 16

typedef __attribute__((ext_vector_type(8))) short bf16x8;
typedef __attribute__((ext_vector_type(4))) float f32x4;

#define MFMA(A, Bv, C) __builtin_amdgcn_mfma_f32_16x16x32_bf16(A, Bv, C, 0, 0, 0)

// frag-buffer element offsets (unsigned short units), per side
#define FR_WI   0
#define FR_WG   32768
#define FR_WPR  65536
#define FR_WPO  73728
#define FR_WD   81920
#define FR_SIDE 90112   // 180224 bytes per side

__device__ __forceinline__ unsigned short f2bf(float f) {
  unsigned u = __float_as_uint(f);
  return (unsigned short)((u + 0x7FFFu + ((u >> 16) & 1u)) >> 16);
}
__device__ __forceinline__ float sigf(float x) {
  return 1.0f / (1.0f + __expf(-x));
}
__device__ __forceinline__ float tanh_f(float x) {
  return 1.0f - 2.0f / (__expf(2.0f * x) + 1.0f);
}

// --- JAX threefry2x32-20 (partitionable) + uniform + XLA ErfInv32 ---
__device__ __forceinline__ float eps_threefry(unsigned seed, unsigned idx) {
  unsigned x0 = 0u, x1 = idx;
  const unsigned ks0 = 0u, ks1 = seed, ks2 = seed ^ 0x1BD11BDAu;
  x0 += ks0; x1 += ks1;
#define TF_R(r) { x0 += x1; x1 = (x1 << (r)) | (x1 >> (32 - (r))); x1 ^= x0; }
  TF_R(13) TF_R(15) TF_R(26) TF_R(6)  x0 += ks1; x1 += ks2 + 1u;
  TF_R(17) TF_R(29) TF_R(16) TF_R(24) x0 += ks2; x1 += ks0 + 2u;
  TF_R(13) TF_R(15) TF_R(26) TF_R(6)  x0 += ks0; x1 += ks1 + 3u;
  TF_R(17) TF_R(29) TF_R(16) TF_R(24) x0 += ks1; x1 += ks2 + 4u;
  TF_R(13) TF_R(15) TF_R(26) TF_R(6)  x0 += ks2; x1 += ks0 + 5u;
#undef TF_R
  unsigned bits = x0 ^ x1;
  unsigned fb = (bits >> 9) | 0x3F800000u;
  const float lo = -0.99999994f;
  float f = __uint_as_float(fb) - 1.0f;
  float u = fmaxf(lo, f * 2.0f + lo);
  float w = -log1pf(-u * u);
  float p;
  if (w < 5.0f) {
    w -= 2.5f;
    p = 2.81022636e-08f;
    p = fmaf(p, w, 3.43273939e-07f);
    p = fmaf(p, w, -3.5233877e-06f);
    p = fmaf(p, w, -4.39150654e-06f);
    p = fmaf(p, w, 0.00021858087f);
    p = fmaf(p, w, -0.00125372503f);
    p = fmaf(p, w, -0.00417768164f);
    p = fmaf(p, w, 0.246640727f);
    p = fmaf(p, w, 1.50140941f);
  } else {
    w = sqrtf(w) - 3.0f;
    p = -0.000200214257f;
    p = fmaf(p, w, 0.000100950558f);
    p = fmaf(p, w, 0.00134934322f);
    p = fmaf(p, w, -0.00367342844f);
    p = fmaf(p, w, 0.00573950773f);
    p = fmaf(p, w, -0.0076224613f);
    p = fmaf(p, w, 0.00943887047f);
    p = fmaf(p, w, 1.00167406f);
    p = fmaf(p, w, 2.83297682f);
  }
  return 1.41421356f * (p * u);
}

// ================= Kernel 1: static precompute (f32, unchanged) ============
template<int LDW>
__device__ __forceinline__ void acc_k16(const float* __restrict__ W, int rowOff, int K,
                                        const float x[][LDW], int j, float* acc) {
  for (int k4 = 0; k4 < K; k4 += 4) {
    float4 xa[RROWS];
    #pragma unroll
    for (int r = 0; r < RROWS; ++r) xa[r] = *(const float4*)&x[r][k4];
    #pragma unroll
    for (int kk = 0; kk < 4; ++kk) {
      float w = W[(size_t)(rowOff + k4 + kk) * 256 + j];
      #pragma unroll
      for (int r = 0; r < RROWS; ++r) {
        float xv = kk == 0 ? xa[r].x : kk == 1 ? xa[r].y : kk == 2 ? xa[r].z : xa[r].w;
        acc[r] = fmaf(xv, w, acc[r]);
      }
    }
  }
}

__global__ __launch_bounds__(256) void GeRN_static(
    const float* __restrict__ cnd, const float* __restrict__ qj,
    const float* __restrict__ qd, const float* __restrict__ qv,
    const float* __restrict__ Wij, const float* __restrict__ bij,
    const float* __restrict__ Wid, const float* __restrict__ bid,
    const float* __restrict__ Wgj, const float* __restrict__ bgj,
    const float* __restrict__ Wgd, const float* __restrict__ bgd,
    float* __restrict__ ws, int B)
{
  __shared__ float sx[RROWS][256];
  __shared__ float sqj[RROWS][64];
  __shared__ float sqd[RROWS][64];
  __shared__ float sqv[RROWS][4];
  const int tid = threadIdx.x;
  const int b0 = blockIdx.x * RROWS;
  for (int i = tid; i < RROWS * 256; i += 256) {
    int r = i >> 8, c = i & 255;
    sx[r][c] = cnd[(size_t)(b0 + r) * 256 + c];
  }
  for (int i = tid; i < RROWS * 64; i += 256) {
    int r = i >> 6, c = i & 63;
    sqj[r][c] = qj[(size_t)(b0 + r) * 64 + c];
    sqd[r][c] = qd[(size_t)(b0 + r) * 64 + c];
  }
  if (tid < RROWS * 4) {
    int r = tid >> 2, c = tid & 3;
    sqv[r][c] = qv[(size_t)(b0 + r) * 4 + c];
  }
  __syncthreads();
  const int j = tid;
  float* pre_ij = ws;
  float* pre_id = ws + (size_t)B * 256;
  float* pre_gj = ws + (size_t)2 * B * 256;
  float* pre_gd = ws + (size_t)3 * B * 256;
  float acc[RROWS];

  {
    float bb = bij[j];
    #pragma unroll
    for (int r = 0; r < RROWS; ++r) acc[r] = bb;
    acc_k16<256>(Wij, 0, 256, sx, j, acc);
    acc_k16<64>(Wij, 256, 64, sqj, j, acc);
    #pragma unroll
    for (int r = 0; r < RROWS; ++r) pre_ij[(size_t)(b0 + r) * 256 + j] = acc[r];
  }
  {
    float bb = bid[j];
    #pragma unroll
    for (int r = 0; r < RROWS; ++r) acc[r] = bb;
    acc_k16<256>(Wid, 0, 256, sx, j, acc);
    acc_k16<64>(Wid, 256, 64, sqd, j, acc);
    #pragma unroll
    for (int r = 0; r < RROWS; ++r) pre_id[(size_t)(b0 + r) * 256 + j] = acc[r];
  }
  {
    float bb = bgj[j];
    #pragma unroll
    for (int r = 0; r < RROWS; ++r) acc[r] = bb;
    acc_k16<256>(Wgj, 0, 256, sx, j, acc);
    #pragma unroll
    for (int r = 0; r < RROWS; ++r) pre_gj[(size_t)(b0 + r) * 256 + j] = acc[r];
  }
  {
    float bb = bgd[j];
    #pragma unroll
    for (int r = 0; r < RROWS; ++r) acc[r] = bb;
    acc_k16<256>(Wgd, 0, 256, sx, j, acc);
    for (int k = 0; k < 4; ++k) {
      float w = Wgd[(size_t)(320 + k) * 256 + j];
      #pragma unroll
      for (int r = 0; r < RROWS; ++r) acc[r] = fmaf(sqv[r][k], w, acc[r]);
    }
    #pragma unroll
    for (int r = 0; r < RROWS; ++r) pre_gd[(size_t)(b0 + r) * 256 + j] = acc[r];
  }
}

// ================= Kernel 2: weight -> bf16 B-fragment prep ================
// B-frag (16x16x32): lane l holds B[k=(l>>4)*8+j][n=l&15], j=0..7 contiguous.
__global__ __launch_bounds__(64) void GeRN_prep(
    const float* __restrict__ Wij, const float* __restrict__ Wid,
    const float* __restrict__ Wgj, const float* __restrict__ Wgd,
    const float* __restrict__ Wprj, const float* __restrict__ Wprd,
    const float* __restrict__ Wpoj, const float* __restrict__ Wpod,
    const float* __restrict__ Wdj, const float* __restrict__ Wdd,
    unsigned short* __restrict__ frB)
{
  const int l = threadIdx.x;
  const int s = blockIdx.x / 176;
  int tt = blockIdx.x % 176;
  const float* W; int ldw, rb, NT, kt, nt; size_t doff;
  if (tt < 64)       { W = s ? Wid : Wij; ldw = 256; NT = 16; kt = tt >> 4; nt = tt & 15;
                       rb = 320 + kt * 32; doff = FR_WI; }
  else if (tt < 128) { tt -= 64; W = s ? Wgd : Wgj; ldw = 256; NT = 16; kt = tt >> 4; nt = tt & 15;
                       rb = (kt < 2) ? 256 + kt * 32 : (s ? 324 : 320) + (kt - 2) * 32; doff = FR_WG; }
  else if (tt < 144) { tt -= 128; W = s ? Wprd : Wprj; ldw = 128; NT = 8; kt = tt >> 3; nt = tt & 7;
                       rb = kt * 32; doff = FR_WPR; }
  else if (tt < 160) { tt -= 144; W = s ? Wpod : Wpoj; ldw = 128; NT = 8; kt = tt >> 3; nt = tt & 7;
                       rb = kt * 32; doff = FR_WPO; }
  else               { tt -= 160; W = s ? Wdd : Wdj; ldw = 64; NT = 4; kt = tt >> 2; nt = tt & 3;
                       rb = (kt < 2) ? kt * 32 : 64 + (kt - 2) * 32; doff = FR_WD; }
  unsigned short* dst = frB + (size_t)s * FR_SIDE + doff
                      + ((size_t)(kt * NT + nt) * 64 + l) * 8;
  const int kk = (l >> 4) * 8;
  const int c = nt * 16 + (l & 15);
  #pragma unroll
  for (int j = 0; j < 8; ++j)
    dst[j] = f2bf(W[(size_t)(rb + kk + j) * ldw + c]);
}

// ================= Kernel 3: MFMA recurrence =================
// A-frag (16x16x32): lane l holds A[row=l&15][k=(l>>4)*8+j], j contiguous.
// state frag buf index: fr[buf][k>>5 (kt)][(row&15)+((k>>3)&3)*16][k&7]

#define WR_FR(buf, row, c, v) \
  fr[buf][(c) >> 5][((row) & 15) + (((c) >> 3) & 3) * 16][(c) & 7] = f2bf(v)
#define LD_FR(buf, kt) (*(const bf16x8*)&fr[buf][kt][l][0])
#define LD_B(off, kt, nt, NT) \
  (*(const bf16x8*)(FB + (off) + (((kt) * (NT) + (nt)) * 64 + l) * 8))

__global__ __launch_bounds__(512, 4) void GeRN_recur(
    const unsigned short* __restrict__ frB,
    const float* __restrict__ pre_ij, const float* __restrict__ pre_id,
    const float* __restrict__ pre_gj, const float* __restrict__ pre_gd,
    const float* __restrict__ bprj, const float* __restrict__ bprd,
    const float* __restrict__ bpoj, const float* __restrict__ bpod,
    const float* __restrict__ bdj,  const float* __restrict__ bdd,
    const float* __restrict__ hi_j0, const float* __restrict__ ci_j0,
    const float* __restrict__ hi_d0, const float* __restrict__ ci_d0,
    const float* __restrict__ hg_j0, const float* __restrict__ cg_j0,
    const float* __restrict__ hg_d0, const float* __restrict__ cg_d0,
    const float* __restrict__ ug_j0, const float* __restrict__ ug_d0,
    float* __restrict__ out, int B, int nd)
{
  // fr bufs: 0 hi_j, 1 hi_d, 2 hg_j, 3 hg_d, 4 z_j, 5 z_d, 6 u_j, 7 u_d
  alignas(16) __shared__ unsigned short fr[8][2][64][8];       // 16 KB
  alignas(16) __shared__ float preL[2][2][4][4][64][4];        // 64 KB (D-layout)

  const int tid = threadIdx.x;
  const int l   = tid & 63;
  const int w   = tid >> 6;
  const int s   = w >> 2;          // 0=j, 1=d (wave-uniform)
  const int ws  = w & 3;
  const int r0  = (l >> 4) * 4;
  const int col = ws * 16 + (l & 15);
  const int bbase = blockIdx.x * 16;
  const size_t BN = (size_t)B * 64;

  const float* hi0 = s ? hi_d0 : hi_j0;  const float* ci0 = s ? ci_d0 : ci_j0;
  const float* hg0 = s ? hg_d0 : hg_j0;  const float* cg0 = s ? cg_d0 : cg_j0;
  const float* ug0 = s ? ug_d0 : ug_j0;
  const float* preIg = s ? pre_id : pre_ij;
  const float* preGg = s ? pre_gd : pre_gj;
  const float* BPR = s ? bprd : bprj;
  const float* BPO = s ? bpod : bpoj;
  const float* BD  = s ? bdd  : bdj;
  const unsigned short* FB = frB + (size_t)s * FR_SIDE;

  float hi_[4], ci_[4], hg_[4], cg_[4], u_[4];
  #pragma unroll
  for (int r = 0; r < 4; ++r) {
    size_t gi = (size_t)(bbase + r0 + r) * 64 + col;
    hi_[r] = hi0[gi]; ci_[r] = ci0[gi];
    hg_[r] = hg0[gi]; cg_[r] = cg0[gi];
    u_[r]  = ug0[gi];
  }
  const float bprm = BPR[col], bprv = BPR[64 + col];
  const float bpom = BPO[col], bpov = BPO[64 + col];
  const float bd   = BD[col];

  #pragma unroll
  for (int g = 0; g < 4; ++g)
    #pragma unroll
    for (int r = 0; r < 4; ++r) {
      preL[s][0][g][ws][l][r] = preIg[(size_t)(bbase + r0 + r) * 256 + g * 64 + col];
      preL[s][1][g][ws][l][r] = preGg[(size_t)(bbase + r0 + r) * 256 + g * 64 + col];
    }
  #pragma unroll
  for (int r = 0; r < 4; ++r) {
    WR_FR(0 + s, r0 + r, col, hi_[r]);
    WR_FR(2 + s, r0 + r, col, hg_[r]);
    WR_FR(6 + s, r0 + r, col, u_[r]);
  }
  __syncthreads();

  const float zo = s ? 0.2f : 0.3f, zo1 = 1.0f - zo;

  for (int t = 0; t < nd; ++t) {
    // ---- P1: A-frags of hg_old, hi_old ----
    bf16x8 a_hg0 = LD_FR(2 + s, 0), a_hg1 = LD_FR(2 + s, 1);
    bf16x8 a_hi0 = LD_FR(0 + s, 0), a_hi1 = LD_FR(0 + s, 1);
    __syncthreads();

    // ---- P2: prior head + inference LSTM ----
    {
      f32x4 am = {bprm, bprm, bprm, bprm};
      f32x4 av = {bprv, bprv, bprv, bprv};
      am = MFMA(a_hg0, LD_B(FR_WPR, 0, ws, 8), am);
      am = MFMA(a_hg1, LD_B(FR_WPR, 1, ws, 8), am);
      av = MFMA(a_hg0, LD_B(FR_WPR, 0, ws + 4, 8), av);
      av = MFMA(a_hg1, LD_B(FR_WPR, 1, ws + 4, 8), av);
      #pragma unroll
      for (int r = 0; r < 4; ++r) {
        size_t gi = (size_t)(bbase + r0 + r) * 64 + col;
        __builtin_nontemporal_store(am[r], out + (size_t)(2 + (2 * s) * nd + t) * BN + gi);
        __builtin_nontemporal_store(av[r], out + (size_t)(2 + (2 * s + 1) * nd + t) * BN + gi);
      }
    }
    {
      f32x4 acc0, acc1, acc2, acc3;
      acc0 = *(const f32x4*)&preL[s][0][0][ws][l][0];
      acc1 = *(const f32x4*)&preL[s][0][1][ws][l][0];
      acc2 = *(const f32x4*)&preL[s][0][2][ws][l][0];
      acc3 = *(const f32x4*)&preL[s][0][3][ws][l][0];
      acc0 = MFMA(a_hg0, LD_B(FR_WI, 0, 0 * 4 + ws, 16), acc0);
      acc0 = MFMA(a_hg1, LD_B(FR_WI, 1, 0 * 4 + ws, 16), acc0);
      acc0 = MFMA(a_hi0, LD_B(FR_WI, 2, 0 * 4 + ws, 16), acc0);
      acc0 = MFMA(a_hi1, LD_B(FR_WI, 3, 0 * 4 + ws, 16), acc0);
      acc1 = MFMA(a_hg0, LD_B(FR_WI, 0, 1 * 4 + ws, 16), acc1);
      acc1 = MFMA(a_hg1, LD_B(FR_WI, 1, 1 * 4 + ws, 16), acc1);
      acc1 = MFMA(a_hi0, LD_B(FR_WI, 2, 1 * 4 + ws, 16), acc1);
      acc1 = MFMA(a_hi1, LD_B(FR_WI, 3, 1 * 4 + ws, 16), acc1);
      acc2 = MFMA(a_hg0, LD_B(FR_WI, 0, 2 * 4 + ws, 16), acc2);
      acc2 = MFMA(a_hg1, LD_B(FR_WI, 1, 2 * 4 + ws, 16), acc2);
      acc2 = MFMA(a_hi0, LD_B(FR_WI, 2, 2 * 4 + ws, 16), acc2);
      acc2 = MFMA(a_hi1, LD_B(FR_WI, 3, 2 * 4 + ws, 16), acc2);
      acc3 = MFMA(a_hg0, LD_B(FR_WI, 0, 3 * 4 + ws, 16), acc3);
      acc3 = MFMA(a_hg1, LD_B(FR_WI, 1, 3 * 4 + ws, 16), acc3);
      acc3 = MFMA(a_hi0, LD_B(FR_WI, 2, 3 * 4 + ws, 16), acc3);
      acc3 = MFMA(a_hi1, LD_B(FR_WI, 3, 3 * 4 + ws, 16), acc3);
      #pragma unroll
      for (int r = 0; r < 4; ++r) {
        float ig = sigf(acc0[r]), fg = sigf(acc1[r]);
        float gg = tanh_f(acc2[r]), og = sigf(acc3[r]);
        float cn = fmaf(fg, ci_[r], ig * gg);
        float hn = og * tanh_f(cn);
        hi_[r] = fmaf(zo, hi_[r], zo1 * hn);
        ci_[r] = fmaf(zo, ci_[r], zo1 * cn);
        WR_FR(0 + s, r0 + r, col, hi_[r]);
      }
    }
    __syncthreads();

    // ---- P3: posterior head + z sample ----
    {
      bf16x8 a0 = LD_FR(0 + s, 0), a1 = LD_FR(0 + s, 1);
      f32x4 am = {bpom, bpom, bpom, bpom};
      f32x4 av = {bpov, bpov, bpov, bpov};
      am = MFMA(a0, LD_B(FR_WPO, 0, ws, 8), am);
      am = MFMA(a1, LD_B(FR_WPO, 1, ws, 8), am);
      av = MFMA(a0, LD_B(FR_WPO, 0, ws + 4, 8), av);
      av = MFMA(a1, LD_B(FR_WPO, 1, ws + 4, 8), av);
      #pragma unroll
      for (int r = 0; r < 4; ++r) {
        size_t gi = (size_t)(bbase + r0 + r) * 64 + col;
        __builtin_nontemporal_store(am[r], out + (size_t)(2 + (4 + 2 * s) * nd + t) * BN + gi);
        __builtin_nontemporal_store(av[r], out + (size_t)(2 + (5 + 2 * s) * nd + t) * BN + gi);
        float e = eps_threefry(1u + (unsigned)s, (unsigned)((size_t)t * BN + gi));
        float z = fmaf(__expf(0.5f * av[r]), e, am[r]);
        WR_FR(4 + s, r0 + r, col, z);
      }
    }
    __syncthreads();

    // ---- P4: generator LSTM (x1 = z, x2 = hg_old) ----
    {
      bf16x8 az0 = LD_FR(4 + s, 0), az1 = LD_FR(4 + s, 1);
      f32x4 acc0, acc1, acc2, acc3;
      acc0 = *(const f32x4*)&preL[s][1][0][ws][l][0];
      acc1 = *(const f32x4*)&preL[s][1][1][ws][l][0];
      acc2 = *(const f32x4*)&preL[s][1][2][ws][l][0];
      acc3 = *(const f32x4*)&preL[s][1][3][ws][l][0];
      acc0 = MFMA(az0,   LD_B(FR_WG, 0, 0 * 4 + ws, 16), acc0);
      acc0 = MFMA(az1,   LD_B(FR_WG, 1, 0 * 4 + ws, 16), acc0);
      acc0 = MFMA(a_hg0, LD_B(FR_WG, 2, 0 * 4 + ws, 16), acc0);
      acc0 = MFMA(a_hg1, LD_B(FR_WG, 3, 0 * 4 + ws, 16), acc0);
      acc1 = MFMA(az0,   LD_B(FR_WG, 0, 1 * 4 + ws, 16), acc1);
      acc1 = MFMA(az1,   LD_B(FR_WG, 1, 1 * 4 + ws, 16), acc1);
      acc1 = MFMA(a_hg0, LD_B(FR_WG, 2, 1 * 4 + ws, 16), acc1);
      acc1 = MFMA(a_hg1, LD_B(FR_WG, 3, 1 * 4 + ws, 16), acc1);
      acc2 = MFMA(az0,   LD_B(FR_WG, 0, 2 * 4 + ws, 16), acc2);
      acc2 = MFMA(az1,   LD_B(FR_WG, 1, 2 * 4 + ws, 16), acc2);
      acc2 = MFMA(a_hg0, LD_B(FR_WG, 2, 2 * 4 + ws, 16), acc2);
      acc2 = MFMA(a_hg1, LD_B(FR_WG, 3, 2 * 4 + ws, 16), acc2);
      acc3 = MFMA(az0,   LD_B(FR_WG, 0, 3 * 4 + ws, 16), acc3);
      acc3 = MFMA(az1,   LD_B(FR_WG, 1, 3 * 4 + ws, 16), acc3);
      acc3 = MFMA(a_hg0, LD_B(FR_WG, 2, 3 * 4 + ws, 16), acc3);
      acc3 = MFMA(a_hg1, LD_B(FR_WG, 3, 3 * 4 + ws, 16), acc3);
      #pragma unroll
      for (int r = 0; r < 4; ++r) {
        float ig = sigf(acc0[r]), fg = sigf(acc1[r]);
        float gg = tanh_f(acc2[r]), og = sigf(acc3[r]);
        float cn = fmaf(fg, cg_[r], ig * gg);
        float hn = og * tanh_f(cn);
        hg_[r] = fmaf(zo, hg_[r], zo1 * hn);
        cg_[r] = fmaf(zo, cg_[r], zo1 * cn);
        WR_FR(2 + s, r0 + r, col, hg_[r]);
      }
    }
    __syncthreads();

    // ---- P5: canvas delta u += leaky(Wd @ [u, hg_new] + b) ----
    bf16x8 au0 = LD_FR(6 + s, 0), au1 = LD_FR(6 + s, 1);
    bf16x8 ah0 = LD_FR(2 + s, 0), ah1 = LD_FR(2 + s, 1);
    __syncthreads();
    {
      f32x4 acc = {bd, bd, bd, bd};
      acc = MFMA(au0, LD_B(FR_WD, 0, ws, 4), acc);
      acc = MFMA(au1, LD_B(FR_WD, 1, ws, 4), acc);
      acc = MFMA(ah0, LD_B(FR_WD, 2, ws, 4), acc);
      acc = MFMA(ah1, LD_B(FR_WD, 3, ws, 4), acc);
      #pragma unroll
      for (int r = 0; r < 4; ++r) {
        float a = acc[r];
        float d = a > 0.0f ? a : 0.01f * a;
        u_[r] += d;
        WR_FR(6 + s, r0 + r, col, u_[r]);
      }
    }
    __syncthreads();
  }

  // ---- final canvases ----
  #pragma unroll
  for (int r = 0; r < 4; ++r) {
    size_t gi = (size_t)(bbase + r0 + r) * 64 + col;
    __builtin_nontemporal_store(u_[r], out + (size_t)s * BN + gi);
  }
}

extern "C" void kernel_launch(void* const* d_in, const int* in_sizes, int n_in,
                              void* d_out, int out_size, void* d_ws, size_t ws_size,
                              hipStream_t stream)
{
  const float* cnd = (const float*)d_in[1];
  const float* qj  = (const float*)d_in[2];
  const float* qd  = (const float*)d_in[3];
  const float* qv  = (const float*)d_in[4];
  const float* hi_j0 = (const float*)d_in[5];
  const float* ci_j0 = (const float*)d_in[6];
  const float* hi_d0 = (const float*)d_in[8];
  const float* ci_d0 = (const float*)d_in[9];
  const float* hg_j0 = (const float*)d_in[11];
  const float* cg_j0 = (const float*)d_in[12];
  const float* hg_d0 = (const float*)d_in[14];
  const float* cg_d0 = (const float*)d_in[15];
  const float* ug_j0 = (const float*)d_in[17];
  const float* ug_d0 = (const float*)d_in[18];
  const float* Wij = (const float*)d_in[19]; const float* bij = (const float*)d_in[20];
  const float* Wid = (const float*)d_in[21]; const float* bid = (const float*)d_in[22];
  const float* Wgj = (const float*)d_in[23]; const float* bgj = (const float*)d_in[24];
  const float* Wgd = (const float*)d_in[25]; const float* bgd = (const float*)d_in[26];
  const float* Wpoj = (const float*)d_in[27]; const float* bpoj = (const float*)d_in[28];
  const float* Wpod = (const float*)d_in[29]; const float* bpod = (const float*)d_in[30];
  const float* Wprj = (const float*)d_in[31]; const float* bprj = (const float*)d_in[32];
  const float* Wprd = (const float*)d_in[33]; const float* bprd = (const float*)d_in[34];
  const float* Wdj = (const float*)d_in[35]; const float* bdj = (const float*)d_in[36];
  const float* Wdd = (const float*)d_in[37]; const float* bdd = (const float*)d_in[38];

  const int B = in_sizes[1] / 256;                 // cnd_repr is [B,256]
  const int slots = out_size / (B * 64);           // 2 + 8*ndraw
  const int nd = (slots - 2) / 8;

  float* ws = (float*)d_ws;                        // pre: 4*B*256 f32 (32 MB)
  unsigned short* frB = (unsigned short*)(ws + (size_t)4 * B * 256);  // +360 KB
  float* out = (float*)d_out;

  GeRN_static<<<B / RROWS, 256, 0, stream>>>(
      cnd, qj, qd, qv, Wij, bij, Wid, bid, Wgj, bgj, Wgd, bgd, ws, B);
  GeRN_prep<<<352, 64, 0, stream>>>(
      Wij, Wid, Wgj, Wgd, Wprj, Wprd, Wpoj, Wpod, Wdj, Wdd, frB);
  GeRN_recur<<<B / 16, 512, 0, stream>>>(
      frB,
      ws, ws + (size_t)B * 256, ws + (size_t)2 * B * 256, ws + (size_t)3 * B * 256,
      bprj, bprd, bpoj, bpod, bdj, bdd,
      hi_j0, ci_j0, hi_d0, ci_d0, hg_j0, cg_j0, hg_d0, cg_d0, ug_j0, ug_d0,
      out, B, nd);
}

// Round 5
// 291.657 us; speedup vs baseline: 214.3531x; 2.1497x over previous
//
#include <hip/hip_runtime.h>
#include <hip/hip_bf16.h>

// GeRN fused, round 5: MFMA recurrence with register-resident B-fragments.
//  kernel1 GeRN_static (f32, unchanged): static gate pre-activations -> ws.
//  kernel2 GeRN_prep (unchanged): dynamic weight rows -> bf16 B-frag in ws.
//  kernel3 GeRN_recur: block = (side, 16 rows), 256 thr = 4 waves.
//    WI/WG/WD B-frags live in VGPRs (loaded once); WPR/WPO in LDS;
//    states f32 in regs, mirrored to bf16 A-frag LDS; pre f32 in LDS.

#define RROWS 16

typedef __attribute__((ext_vector_type(8))) short bf16x8;
typedef __attribute__((ext_vector_type(4))) float f32x4;

#define MFMA(A, Bv, C) __builtin_amdgcn_mfma_f32_16x16x32_bf16(A, Bv, C, 0, 0, 0)

// frag-buffer element offsets (unsigned short units), per side
#define FR_WI   0
#define FR_WG   32768
#define FR_WPR  65536
#define FR_WPO  73728
#define FR_WD   81920
#define FR_SIDE 90112   // 180224 bytes per side

__device__ __forceinline__ unsigned short f2bf(float f) {
  unsigned u = __float_as_uint(f);
  return (unsigned short)((u + 0x7FFFu + ((u >> 16) & 1u)) >> 16);
}
__device__ __forceinline__ float sigf(float x) {
  return 1.0f / (1.0f + __expf(-x));
}
__device__ __forceinline__ float tanh_f(float x) {
  return 1.0f - 2.0f / (__expf(2.0f * x) + 1.0f);
}

// --- JAX threefry2x32-20 (partitionable) + uniform + XLA ErfInv32 ---
__device__ __forceinline__ float eps_threefry(unsigned seed, unsigned idx) {
  unsigned x0 = 0u, x1 = idx;
  const unsigned ks0 = 0u, ks1 = seed, ks2 = seed ^ 0x1BD11BDAu;
  x0 += ks0; x1 += ks1;
#define TF_R(r) { x0 += x1; x1 = (x1 << (r)) | (x1 >> (32 - (r))); x1 ^= x0; }
  TF_R(13) TF_R(15) TF_R(26) TF_R(6)  x0 += ks1; x1 += ks2 + 1u;
  TF_R(17) TF_R(29) TF_R(16) TF_R(24) x0 += ks2; x1 += ks0 + 2u;
  TF_R(13) TF_R(15) TF_R(26) TF_R(6)  x0 += ks0; x1 += ks1 + 3u;
  TF_R(17) TF_R(29) TF_R(16) TF_R(24) x0 += ks1; x1 += ks2 + 4u;
  TF_R(13) TF_R(15) TF_R(26) TF_R(6)  x0 += ks2; x1 += ks0 + 5u;
#undef TF_R
  unsigned bits = x0 ^ x1;
  unsigned fb = (bits >> 9) | 0x3F800000u;
  const float lo = -0.99999994f;
  float f = __uint_as_float(fb) - 1.0f;
  float u = fmaxf(lo, f * 2.0f + lo);
  float w = -log1pf(-u * u);
  float p;
  if (w < 5.0f) {
    w -= 2.5f;
    p = 2.81022636e-08f;
    p = fmaf(p, w, 3.43273939e-07f);
    p = fmaf(p, w, -3.5233877e-06f);
    p = fmaf(p, w, -4.39150654e-06f);
    p = fmaf(p, w, 0.00021858087f);
    p = fmaf(p, w, -0.00125372503f);
    p = fmaf(p, w, -0.00417768164f);
    p = fmaf(p, w, 0.246640727f);
    p = fmaf(p, w, 1.50140941f);
  } else {
    w = sqrtf(w) - 3.0f;
    p = -0.000200214257f;
    p = fmaf(p, w, 0.000100950558f);
    p = fmaf(p, w, 0.00134934322f);
    p = fmaf(p, w, -0.00367342844f);
    p = fmaf(p, w, 0.00573950773f);
    p = fmaf(p, w, -0.0076224613f);
    p = fmaf(p, w, 0.00943887047f);
    p = fmaf(p, w, 1.00167406f);
    p = fmaf(p, w, 2.83297682f);
  }
  return 1.41421356f * (p * u);
}

// ================= Kernel 1: static precompute (f32, unchanged) ============
template<int LDW>
__device__ __forceinline__ void acc_k16(const float* __restrict__ W, int rowOff, int K,
                                        const float x[][LDW], int j, float* acc) {
  for (int k4 = 0; k4 < K; k4 += 4) {
    float4 xa[RROWS];
    #pragma unroll
    for (int r = 0; r < RROWS; ++r) xa[r] = *(const float4*)&x[r][k4];
    #pragma unroll
    for (int kk = 0; kk < 4; ++kk) {
      float w = W[(size_t)(rowOff + k4 + kk) * 256 + j];
      #pragma unroll
      for (int r = 0; r < RROWS; ++r) {
        float xv = kk == 0 ? xa[r].x : kk == 1 ? xa[r].y : kk == 2 ? xa[r].z : xa[r].w;
        acc[r] = fmaf(xv, w, acc[r]);
      }
    }
  }
}

__global__ __launch_bounds__(256) void GeRN_static(
    const float* __restrict__ cnd, const float* __restrict__ qj,
    const float* __restrict__ qd, const float* __restrict__ qv,
    const float* __restrict__ Wij, const float* __restrict__ bij,
    const float* __restrict__ Wid, const float* __restrict__ bid,
    const float* __restrict__ Wgj, const float* __restrict__ bgj,
    const float* __restrict__ Wgd, const float* __restrict__ bgd,
    float* __restrict__ ws, int B)
{
  __shared__ float sx[RROWS][256];
  __shared__ float sqj[RROWS][64];
  __shared__ float sqd[RROWS][64];
  __shared__ float sqv[RROWS][4];
  const int tid = threadIdx.x;
  const int b0 = blockIdx.x * RROWS;
  for (int i = tid; i < RROWS * 256; i += 256) {
    int r = i >> 8, c = i & 255;
    sx[r][c] = cnd[(size_t)(b0 + r) * 256 + c];
  }
  for (int i = tid; i < RROWS * 64; i += 256) {
    int r = i >> 6, c = i & 63;
    sqj[r][c] = qj[(size_t)(b0 + r) * 64 + c];
    sqd[r][c] = qd[(size_t)(b0 + r) * 64 + c];
  }
  if (tid < RROWS * 4) {
    int r = tid >> 2, c = tid & 3;
    sqv[r][c] = qv[(size_t)(b0 + r) * 4 + c];
  }
  __syncthreads();
  const int j = tid;
  float* pre_ij = ws;
  float* pre_id = ws + (size_t)B * 256;
  float* pre_gj = ws + (size_t)2 * B * 256;
  float* pre_gd = ws + (size_t)3 * B * 256;
  float acc[RROWS];

  {
    float bb = bij[j];
    #pragma unroll
    for (int r = 0; r < RROWS; ++r) acc[r] = bb;
    acc_k16<256>(Wij, 0, 256, sx, j, acc);
    acc_k16<64>(Wij, 256, 64, sqj, j, acc);
    #pragma unroll
    for (int r = 0; r < RROWS; ++r) pre_ij[(size_t)(b0 + r) * 256 + j] = acc[r];
  }
  {
    float bb = bid[j];
    #pragma unroll
    for (int r = 0; r < RROWS; ++r) acc[r] = bb;
    acc_k16<256>(Wid, 0, 256, sx, j, acc);
    acc_k16<64>(Wid, 256, 64, sqd, j, acc);
    #pragma unroll
    for (int r = 0; r < RROWS; ++r) pre_id[(size_t)(b0 + r) * 256 + j] = acc[r];
  }
  {
    float bb = bgj[j];
    #pragma unroll
    for (int r = 0; r < RROWS; ++r) acc[r] = bb;
    acc_k16<256>(Wgj, 0, 256, sx, j, acc);
    #pragma unroll
    for (int r = 0; r < RROWS; ++r) pre_gj[(size_t)(b0 + r) * 256 + j] = acc[r];
  }
  {
    float bb = bgd[j];
    #pragma unroll
    for (int r = 0; r < RROWS; ++r) acc[r] = bb;
    acc_k16<256>(Wgd, 0, 256, sx, j, acc);
    for (int k = 0; k < 4; ++k) {
      float w = Wgd[(size_t)(320 + k) * 256 + j];
      #pragma unroll
      for (int r = 0; r < RROWS; ++r) acc[r] = fmaf(sqv[r][k], w, acc[r]);
    }
    #pragma unroll
    for (int r = 0; r < RROWS; ++r) pre_gd[(size_t)(b0 + r) * 256 + j] = acc[r];
  }
}

// ================= Kernel 2: weight -> bf16 B-fragment prep ================
// B-frag (16x16x32): lane l holds B[k=(l>>4)*8+j][n=l&15], j=0..7 contiguous.
__global__ __launch_bounds__(64) void GeRN_prep(
    const float* __restrict__ Wij, const float* __restrict__ Wid,
    const float* __restrict__ Wgj, const float* __restrict__ Wgd,
    const float* __restrict__ Wprj, const float* __restrict__ Wprd,
    const float* __restrict__ Wpoj, const float* __restrict__ Wpod,
    const float* __restrict__ Wdj, const float* __restrict__ Wdd,
    unsigned short* __restrict__ frB)
{
  const int l = threadIdx.x;
  const int s = blockIdx.x / 176;
  int tt = blockIdx.x % 176;
  const float* W; int ldw, rb, NT, kt, nt; size_t doff;
  if (tt < 64)       { W = s ? Wid : Wij; ldw = 256; NT = 16; kt = tt >> 4; nt = tt & 15;
                       rb = 320 + kt * 32; doff = FR_WI; }
  else if (tt < 128) { tt -= 64; W = s ? Wgd : Wgj; ldw = 256; NT = 16; kt = tt >> 4; nt = tt & 15;
                       rb = (kt < 2) ? 256 + kt * 32 : (s ? 324 : 320) + (kt - 2) * 32; doff = FR_WG; }
  else if (tt < 144) { tt -= 128; W = s ? Wprd : Wprj; ldw = 128; NT = 8; kt = tt >> 3; nt = tt & 7;
                       rb = kt * 32; doff = FR_WPR; }
  else if (tt < 160) { tt -= 144; W = s ? Wpod : Wpoj; ldw = 128; NT = 8; kt = tt >> 3; nt = tt & 7;
                       rb = kt * 32; doff = FR_WPO; }
  else               { tt -= 160; W = s ? Wdd : Wdj; ldw = 64; NT = 4; kt = tt >> 2; nt = tt & 3;
                       rb = (kt < 2) ? kt * 32 : 64 + (kt - 2) * 32; doff = FR_WD; }
  unsigned short* dst = frB + (size_t)s * FR_SIDE + doff
                      + ((size_t)(kt * NT + nt) * 64 + l) * 8;
  const int kk = (l >> 4) * 8;
  const int c = nt * 16 + (l & 15);
  #pragma unroll
  for (int j = 0; j < 8; ++j)
    dst[j] = f2bf(W[(size_t)(rb + kk + j) * ldw + c]);
}

// ================= Kernel 3: MFMA recurrence, B in registers ===============
// A-frag (16x16x32): lane l holds A[row=l&15][k=(l>>4)*8+j], j contiguous.
// fr bufs: 0 hi, 1 hg, 2 z, 3 u (own side only).

#define WR_FR(buf, row, c, v) \
  fr[buf][(c) >> 5][((row) & 15) + (((c) >> 3) & 3) * 16][(c) & 7] = f2bf(v)
#define LD_FR(buf, kt) (*(const bf16x8*)&fr[buf][kt][l][0])
#define LD_B(off, kt, nt, NT) \
  (*(const bf16x8*)(FB + (off) + (((kt) * (NT) + (nt)) * 64 + l) * 8))
#define LD_H(ph, kt, nt) \
  (*(const bf16x8*)&shH[(ph) * 8192 + (((kt) * 8 + (nt)) * 64 + l) * 8])

__global__ __launch_bounds__(256, 2) void GeRN_recur(
    const unsigned short* __restrict__ frB,
    const float* __restrict__ pre_ij, const float* __restrict__ pre_id,
    const float* __restrict__ pre_gj, const float* __restrict__ pre_gd,
    const float* __restrict__ bprj, const float* __restrict__ bprd,
    const float* __restrict__ bpoj, const float* __restrict__ bpod,
    const float* __restrict__ bdj,  const float* __restrict__ bdd,
    const float* __restrict__ hi_j0, const float* __restrict__ ci_j0,
    const float* __restrict__ hi_d0, const float* __restrict__ ci_d0,
    const float* __restrict__ hg_j0, const float* __restrict__ cg_j0,
    const float* __restrict__ hg_d0, const float* __restrict__ cg_d0,
    const float* __restrict__ ug_j0, const float* __restrict__ ug_d0,
    float* __restrict__ out, int B, int nd)
{
  alignas(16) __shared__ unsigned short fr[4][2][64][8];     // 8 KB
  alignas(16) __shared__ float preL[2][4][4][64][4];         // 32 KB
  alignas(16) __shared__ unsigned short shH[16384];          // 32 KB (WPR|WPO)

  const int tid = threadIdx.x;
  const int l   = tid & 63;
  const int wv  = tid >> 6;        // wave 0..3 (column slice)
  const int s   = blockIdx.x & 1;  // 0=j, 1=d
  const int rbk = blockIdx.x >> 1;
  const int r0  = (l >> 4) * 4;
  const int col = wv * 16 + (l & 15);
  const int bbase = rbk * 16;
  const size_t BN = (size_t)B * 64;

  const float* hi0 = s ? hi_d0 : hi_j0;  const float* ci0 = s ? ci_d0 : ci_j0;
  const float* hg0 = s ? hg_d0 : hg_j0;  const float* cg0 = s ? cg_d0 : cg_j0;
  const float* ug0 = s ? ug_d0 : ug_j0;
  const float* preIg = s ? pre_id : pre_ij;
  const float* preGg = s ? pre_gd : pre_gj;
  const float* BPR = s ? bprd : bprj;
  const float* BPO = s ? bpod : bpoj;
  const float* BD  = s ? bdd  : bdj;
  const unsigned short* FB = frB + (size_t)s * FR_SIDE;

  // ---- persistent B-fragments in registers ----
  bf16x8 wi[4][4], wg[4][4], wd[4];
  #pragma unroll
  for (int kt = 0; kt < 4; ++kt) {
    #pragma unroll
    for (int g = 0; g < 4; ++g) {
      wi[kt][g] = LD_B(FR_WI, kt, g * 4 + wv, 16);
      wg[kt][g] = LD_B(FR_WG, kt, g * 4 + wv, 16);
    }
    wd[kt] = LD_B(FR_WD, kt, wv, 4);
  }
  // ---- WPR|WPO -> LDS (32 KB contiguous) ----
  {
    const float4* src = (const float4*)(FB + FR_WPR);
    float4* dst = (float4*)shH;
    for (int i = tid; i < 2048; i += 256) dst[i] = src[i];
  }

  // ---- states ----
  float hi_[4], ci_[4], hg_[4], cg_[4], u_[4];
  #pragma unroll
  for (int r = 0; r < 4; ++r) {
    size_t gi = (size_t)(bbase + r0 + r) * 64 + col;
    hi_[r] = hi0[gi]; ci_[r] = ci0[gi];
    hg_[r] = hg0[gi]; cg_[r] = cg0[gi];
    u_[r]  = ug0[gi];
  }
  const float bprm = BPR[col], bprv = BPR[64 + col];
  const float bpom = BPO[col], bpov = BPO[64 + col];
  const float bd   = BD[col];

  #pragma unroll
  for (int g = 0; g < 4; ++g)
    #pragma unroll
    for (int r = 0; r < 4; ++r) {
      preL[0][g][wv][l][r] = preIg[(size_t)(bbase + r0 + r) * 256 + g * 64 + col];
      preL[1][g][wv][l][r] = preGg[(size_t)(bbase + r0 + r) * 256 + g * 64 + col];
    }
  #pragma unroll
  for (int r = 0; r < 4; ++r) {
    WR_FR(0, r0 + r, col, hi_[r]);
    WR_FR(1, r0 + r, col, hg_[r]);
    WR_FR(3, r0 + r, col, u_[r]);
  }
  __syncthreads();

  const float zo = s ? 0.2f : 0.3f, zo1 = 1.0f - zo;

  for (int t = 0; t < nd; ++t) {
    // ---- P1: A-frags of hg_old, hi_old ----
    bf16x8 a_hg0 = LD_FR(1, 0), a_hg1 = LD_FR(1, 1);
    bf16x8 a_hi0 = LD_FR(0, 0), a_hi1 = LD_FR(0, 1);
    __syncthreads();                                 // B1

    // ---- P2: prior head + inference LSTM ----
    {
      f32x4 am = {bprm, bprm, bprm, bprm};
      f32x4 av = {bprv, bprv, bprv, bprv};
      am = MFMA(a_hg0, LD_H(0, 0, wv), am);
      am = MFMA(a_hg1, LD_H(0, 1, wv), am);
      av = MFMA(a_hg0, LD_H(0, 0, wv + 4), av);
      av = MFMA(a_hg1, LD_H(0, 1, wv + 4), av);
      #pragma unroll
      for (int r = 0; r < 4; ++r) {
        size_t gi = (size_t)(bbase + r0 + r) * 64 + col;
        out[(size_t)(2 + (2 * s) * nd + t) * BN + gi] = am[r];
        out[(size_t)(2 + (2 * s + 1) * nd + t) * BN + gi] = av[r];
      }
    }
    {
      f32x4 acc[4];
      #pragma unroll
      for (int g = 0; g < 4; ++g) acc[g] = *(const f32x4*)&preL[0][g][wv][l][0];
      #pragma unroll
      for (int g = 0; g < 4; ++g) {
        acc[g] = MFMA(a_hg0, wi[0][g], acc[g]);
        acc[g] = MFMA(a_hg1, wi[1][g], acc[g]);
        acc[g] = MFMA(a_hi0, wi[2][g], acc[g]);
        acc[g] = MFMA(a_hi1, wi[3][g], acc[g]);
      }
      #pragma unroll
      for (int r = 0; r < 4; ++r) {
        float ig = sigf(acc[0][r]), fg = sigf(acc[1][r]);
        float gg = tanh_f(acc[2][r]), og = sigf(acc[3][r]);
        float cn = fmaf(fg, ci_[r], ig * gg);
        float hn = og * tanh_f(cn);
        hi_[r] = fmaf(zo, hi_[r], zo1 * hn);
        ci_[r] = fmaf(zo, ci_[r], zo1 * cn);
        WR_FR(0, r0 + r, col, hi_[r]);
      }
    }
    __syncthreads();                                 // B2

    // ---- P3: posterior head + z sample ----
    {
      bf16x8 a0 = LD_FR(0, 0), a1 = LD_FR(0, 1);
      f32x4 am = {bpom, bpom, bpom, bpom};
      f32x4 av = {bpov, bpov, bpov, bpov};
      am = MFMA(a0, LD_H(1, 0, wv), am);
      am = MFMA(a1, LD_H(1, 1, wv), am);
      av = MFMA(a0, LD_H(1, 0, wv + 4), av);
      av = MFMA(a1, LD_H(1, 1, wv + 4), av);
      #pragma unroll
      for (int r = 0; r < 4; ++r) {
        size_t gi = (size_t)(bbase + r0 + r) * 64 + col;
        out[(size_t)(2 + (4 + 2 * s) * nd + t) * BN + gi] = am[r];
        out[(size_t)(2 + (5 + 2 * s) * nd + t) * BN + gi] = av[r];
        float e = eps_threefry(1u + (unsigned)s, (unsigned)((size_t)t * BN + gi));
        float z = fmaf(__expf(0.5f * av[r]), e, am[r]);
        WR_FR(2, r0 + r, col, z);
      }
    }
    __syncthreads();                                 // B3

    // ---- P4: generator LSTM (x1 = z, x2 = hg_old) ----
    {
      bf16x8 az0 = LD_FR(2, 0), az1 = LD_FR(2, 1);
      f32x4 acc[4];
      #pragma unroll
      for (int g = 0; g < 4; ++g) acc[g] = *(const f32x4*)&preL[1][g][wv][l][0];
      #pragma unroll
      for (int g = 0; g < 4; ++g) {
        acc[g] = MFMA(az0,   wg[0][g], acc[g]);
        acc[g] = MFMA(az1,   wg[1][g], acc[g]);
        acc[g] = MFMA(a_hg0, wg[2][g], acc[g]);
        acc[g] = MFMA(a_hg1, wg[3][g], acc[g]);
      }
      #pragma unroll
      for (int r = 0; r < 4; ++r) {
        float ig = sigf(acc[0][r]), fg = sigf(acc[1][r]);
        float gg = tanh_f(acc[2][r]), og = sigf(acc[3][r]);
        float cn = fmaf(fg, cg_[r], ig * gg);
        float hn = og * tanh_f(cn);
        hg_[r] = fmaf(zo, hg_[r], zo1 * hn);
        cg_[r] = fmaf(zo, cg_[r], zo1 * cn);
        WR_FR(1, r0 + r, col, hg_[r]);
      }
    }
    __syncthreads();                                 // B4

    // ---- P5: canvas delta u += leaky(Wd @ [u, hg_new] + b) ----
    {
      bf16x8 au0 = LD_FR(3, 0), au1 = LD_FR(3, 1);
      bf16x8 ah0 = LD_FR(1, 0), ah1 = LD_FR(1, 1);
      __syncthreads();                               // B5 (read-before-write)
      f32x4 acc = {bd, bd, bd, bd};
      acc = MFMA(au0, wd[0], acc);
      acc = MFMA(au1, wd[1], acc);
      acc = MFMA(ah0, wd[2], acc);
      acc = MFMA(ah1, wd[3], acc);
      #pragma unroll
      for (int r = 0; r < 4; ++r) {
        float a = acc[r];
        float d = a > 0.0f ? a : 0.01f * a;
        u_[r] += d;
        WR_FR(3, r0 + r, col, u_[r]);
      }
    }
    __syncthreads();                                 // B6 (u visible; hg/hi stable for next P1)
  }

  // ---- final canvases ----
  #pragma unroll
  for (int r = 0; r < 4; ++r) {
    size_t gi = (size_t)(bbase + r0 + r) * 64 + col;
    out[(size_t)s * BN + gi] = u_[r];
  }
}

extern "C" void kernel_launch(void* const* d_in, const int* in_sizes, int n_in,
                              void* d_out, int out_size, void* d_ws, size_t ws_size,
                              hipStream_t stream)
{
  const float* cnd = (const float*)d_in[1];
  const float* qj  = (const float*)d_in[2];
  const float* qd  = (const float*)d_in[3];
  const float* qv  = (const float*)d_in[4];
  const float* hi_j0 = (const float*)d_in[5];
  const float* ci_j0 = (const float*)d_in[6];
  const float* hi_d0 = (const float*)d_in[8];
  const float* ci_d0 = (const float*)d_in[9];
  const float* hg_j0 = (const float*)d_in[11];
  const float* cg_j0 = (const float*)d_in[12];
  const float* hg_d0 = (const float*)d_in[14];
  const float* cg_d0 = (const float*)d_in[15];
  const float* ug_j0 = (const float*)d_in[17];
  const float* ug_d0 = (const float*)d_in[18];
  const float* Wij = (const float*)d_in[19]; const float* bij = (const float*)d_in[20];
  const float* Wid = (const float*)d_in[21]; const float* bid = (const float*)d_in[22];
  const float* Wgj = (const float*)d_in[23]; const float* bgj = (const float*)d_in[24];
  const float* Wgd = (const float*)d_in[25]; const float* bgd = (const float*)d_in[26];
  const float* Wpoj = (const float*)d_in[27]; const float* bpoj = (const float*)d_in[28];
  const float* Wpod = (const float*)d_in[29]; const float* bpod = (const float*)d_in[30];
  const float* Wprj = (const float*)d_in[31]; const float* bprj = (const float*)d_in[32];
  const float* Wprd = (const float*)d_in[33]; const float* bprd = (const float*)d_in[34];
  const float* Wdj = (const float*)d_in[35]; const float* bdj = (const float*)d_in[36];
  const float* Wdd = (const float*)d_in[37]; const float* bdd = (const float*)d_in[38];

  const int B = in_sizes[1] / 256;                 // cnd_repr is [B,256]
  const int slots = out_size / (B * 64);           // 2 + 8*ndraw
  const int nd = (slots - 2) / 8;

  float* ws = (float*)d_ws;                        // pre: 4*B*256 f32 (32 MB)
  unsigned short* frB = (unsigned short*)(ws + (size_t)4 * B * 256);  // +360 KB
  float* out = (float*)d_out;

  GeRN_static<<<B / RROWS, 256, 0, stream>>>(
      cnd, qj, qd, qv, Wij, bij, Wid, bid, Wgj, bgj, Wgd, bgd, ws, B);
  GeRN_prep<<<352, 64, 0, stream>>>(
      Wij, Wid, Wgj, Wgd, Wprj, Wprd, Wpoj, Wpod, Wdj, Wdd, frB);
  GeRN_recur<<<2 * (B / 16), 256, 0, stream>>>(
      frB,
      ws, ws + (size_t)B * 256, ws + (size_t)2 * B * 256, ws + (size_t)3 * B * 256,
      bprj, bprd, bpoj, bpod, bdj, bdd,
      hi_j0, ci_j0, hi_d0, ci_d0, hg_j0, cg_j0, hg_d0, cg_d0, ug_j0, ug_d0,
      out, B, nd);
}

// Round 6
// 239.488 us; speedup vs baseline: 261.0471x; 1.2178x over previous
//
#include <hip/hip_runtime.h>
#include <hip/hip_bf16.h>

// GeRN fused, round 6:
//  GeRN_prep   : dynamic weight rows -> bf16 B-frags (frB) AND static weight
//                rows -> bf16 B-frags (sBs). 944 blocks x 64.
//  GeRN_staticM: static gate pre-activations via MFMA (32 rows/block).
//  GeRN_recur  : as round 5 + double-buffered hi/u frags (4 barriers/step)
//                + hoisted out-pointers and eps counters.

#define RROWS 16

typedef __attribute__((ext_vector_type(8))) short bf16x8;
typedef __attribute__((ext_vector_type(4))) float f32x4;

#define MFMA(A, Bv, C) __builtin_amdgcn_mfma_f32_16x16x32_bf16(A, Bv, C, 0, 0, 0)

// frag-buffer element offsets (unsigned short units), per side
#define FR_WI   0
#define FR_WG   32768
#define FR_WPR  65536
#define FR_WPO  73728
#define FR_WD   81920
#define FR_SIDE 90112   // per side

__device__ __forceinline__ unsigned short f2bf(float f) {
  unsigned u = __float_as_uint(f);
  return (unsigned short)((u + 0x7FFFu + ((u >> 16) & 1u)) >> 16);
}
__device__ __forceinline__ unsigned pk2(float a, float b) {
  return (unsigned)f2bf(a) | ((unsigned)f2bf(b) << 16);
}
__device__ __forceinline__ float sigf(float x) {
  return 1.0f / (1.0f + __expf(-x));
}
__device__ __forceinline__ float tanh_f(float x) {
  return 1.0f - 2.0f / (__expf(2.0f * x) + 1.0f);
}

// --- JAX threefry2x32-20 (partitionable) + uniform + XLA ErfInv32 ---
__device__ __forceinline__ float eps_threefry(unsigned seed, unsigned idx) {
  unsigned x0 = 0u, x1 = idx;
  const unsigned ks0 = 0u, ks1 = seed, ks2 = seed ^ 0x1BD11BDAu;
  x0 += ks0; x1 += ks1;
#define TF_R(r) { x0 += x1; x1 = (x1 << (r)) | (x1 >> (32 - (r))); x1 ^= x0; }
  TF_R(13) TF_R(15) TF_R(26) TF_R(6)  x0 += ks1; x1 += ks2 + 1u;
  TF_R(17) TF_R(29) TF_R(16) TF_R(24) x0 += ks2; x1 += ks0 + 2u;
  TF_R(13) TF_R(15) TF_R(26) TF_R(6)  x0 += ks0; x1 += ks1 + 3u;
  TF_R(17) TF_R(29) TF_R(16) TF_R(24) x0 += ks1; x1 += ks2 + 4u;
  TF_R(13) TF_R(15) TF_R(26) TF_R(6)  x0 += ks2; x1 += ks0 + 5u;
#undef TF_R
  unsigned bits = x0 ^ x1;
  unsigned fb = (bits >> 9) | 0x3F800000u;
  const float lo = -0.99999994f;
  float f = __uint_as_float(fb) - 1.0f;
  float u = fmaxf(lo, f * 2.0f + lo);
  float w = -log1pf(-u * u);
  float p;
  if (w < 5.0f) {
    w -= 2.5f;
    p = 2.81022636e-08f;
    p = fmaf(p, w, 3.43273939e-07f);
    p = fmaf(p, w, -3.5233877e-06f);
    p = fmaf(p, w, -4.39150654e-06f);
    p = fmaf(p, w, 0.00021858087f);
    p = fmaf(p, w, -0.00125372503f);
    p = fmaf(p, w, -0.00417768164f);
    p = fmaf(p, w, 0.246640727f);
    p = fmaf(p, w, 1.50140941f);
  } else {
    w = sqrtf(w) - 3.0f;
    p = -0.000200214257f;
    p = fmaf(p, w, 0.000100950558f);
    p = fmaf(p, w, 0.00134934322f);
    p = fmaf(p, w, -0.00367342844f);
    p = fmaf(p, w, 0.00573950773f);
    p = fmaf(p, w, -0.0076224613f);
    p = fmaf(p, w, 0.00943887047f);
    p = fmaf(p, w, 1.00167406f);
    p = fmaf(p, w, 2.83297682f);
  }
  return 1.41421356f * (p * u);
}

// ============ Kernel 1: prep — all weights to bf16 B-frag layout ===========
// B-frag (16x16x32): lane l holds B[k=(l>>4)*8+j][n=l&15], j contiguous.
// blocks 0..351: dynamic frags (frB) as before.
// blocks 352..943: static frags (sBs): 592 tiles; mats ij(10kt) id(10kt)
//   gj(8kt) gd(9kt, kt8 = qv rows 320..323 + zero pad), 16 nt each.
__global__ __launch_bounds__(64) void GeRN_prep(
    const float* __restrict__ Wij, const float* __restrict__ Wid,
    const float* __restrict__ Wgj, const float* __restrict__ Wgd,
    const float* __restrict__ Wprj, const float* __restrict__ Wprd,
    const float* __restrict__ Wpoj, const float* __restrict__ Wpod,
    const float* __restrict__ Wdj, const float* __restrict__ Wdd,
    unsigned short* __restrict__ frB, unsigned short* __restrict__ sBs)
{
  const int l = threadIdx.x;
  if (blockIdx.x < 352) {
    const int s = blockIdx.x / 176;
    int tt = blockIdx.x % 176;
    const float* W; int ldw, rb, NT, kt, nt; size_t doff;
    if (tt < 64)       { W = s ? Wid : Wij; ldw = 256; NT = 16; kt = tt >> 4; nt = tt & 15;
                         rb = 320 + kt * 32; doff = FR_WI; }
    else if (tt < 128) { tt -= 64; W = s ? Wgd : Wgj; ldw = 256; NT = 16; kt = tt >> 4; nt = tt & 15;
                         rb = (kt < 2) ? 256 + kt * 32 : (s ? 324 : 320) + (kt - 2) * 32; doff = FR_WG; }
    else if (tt < 144) { tt -= 128; W = s ? Wprd : Wprj; ldw = 128; NT = 8; kt = tt >> 3; nt = tt & 7;
                         rb = kt * 32; doff = FR_WPR; }
    else if (tt < 160) { tt -= 144; W = s ? Wpod : Wpoj; ldw = 128; NT = 8; kt = tt >> 3; nt = tt & 7;
                         rb = kt * 32; doff = FR_WPO; }
    else               { tt -= 160; W = s ? Wdd : Wdj; ldw = 64; NT = 4; kt = tt >> 2; nt = tt & 3;
                         rb = (kt < 2) ? kt * 32 : 64 + (kt - 2) * 32; doff = FR_WD; }
    unsigned short* dst = frB + (size_t)s * FR_SIDE + doff
                        + ((size_t)(kt * NT + nt) * 64 + l) * 8;
    const int kk = (l >> 4) * 8;
    const int c = nt * 16 + (l & 15);
    #pragma unroll
    for (int j = 0; j < 8; ++j)
      dst[j] = f2bf(W[(size_t)(rb + kk + j) * ldw + c]);
  } else {
    int bb = blockIdx.x - 352;        // tile id 0..591
    int mat, base;
    if (bb < 160)      { mat = 0; base = 0; }
    else if (bb < 320) { mat = 1; base = 160; }
    else if (bb < 448) { mat = 2; base = 320; }
    else               { mat = 3; base = 448; }
    int tt = bb - base;
    int kk = tt >> 4, nt = tt & 15;
    const float* W = mat == 0 ? Wij : mat == 1 ? Wid : mat == 2 ? Wgj : Wgd;
    const int c = nt * 16 + (l & 15);
    const int kl0 = (l >> 4) * 8;
    unsigned short* dst = sBs + ((size_t)bb * 64 + l) * 8;
    if (mat == 3 && kk == 8) {          // qv rows 320..323 + zero pad
      #pragma unroll
      for (int j = 0; j < 8; ++j) {
        int klo = kl0 + j;
        dst[j] = (klo < 4) ? f2bf(W[(size_t)(320 + klo) * 256 + c]) : (unsigned short)0;
      }
    } else {
      int rb = (kk < 8) ? kk * 32 : 256 + (kk - 8) * 32;
      #pragma unroll
      for (int j = 0; j < 8; ++j)
        dst[j] = f2bf(W[(size_t)(rb + kl0 + j) * 256 + c]);
    }
  }
}

// ============ Kernel 2: static pre-activations via MFMA ====================
// 32 rows/block, 256 thr = 4 waves; wave wv owns 64-col slice of each matrix.
// A kts: 0..7 cnd, 8..9 qj, 10..11 qd, 12 qv(+pad).
__global__ __launch_bounds__(256) void GeRN_staticM(
    const float* __restrict__ cnd, const float* __restrict__ qj,
    const float* __restrict__ qd, const float* __restrict__ qv,
    const float* __restrict__ bij, const float* __restrict__ bid,
    const float* __restrict__ bgj, const float* __restrict__ bgd,
    const unsigned short* __restrict__ sBs,
    float* __restrict__ pre, int B)
{
  alignas(16) __shared__ unsigned short As[13][2][64][8];   // 26 KB
  const int tid = threadIdx.x;
  const int l = tid & 63;
  const int wv = tid >> 6;
  const int b0 = blockIdx.x * 32;

  // ---- stage A-frags (rows b0..b0+31, k-regions cnd|qj|qd|qv) ----
  for (int i = tid; i < 32 * 52; i += 256) {
    int r = i / 52, kc = i % 52;
    int mf = r >> 4, rr = r & 15;
    float v[8];
    if (kc < 32) {
      const float4* p = (const float4*)&cnd[(size_t)(b0 + r) * 256 + kc * 8];
      float4 x0 = p[0], x1 = p[1];
      v[0] = x0.x; v[1] = x0.y; v[2] = x0.z; v[3] = x0.w;
      v[4] = x1.x; v[5] = x1.y; v[6] = x1.z; v[7] = x1.w;
    } else if (kc < 40) {
      const float4* p = (const float4*)&qj[(size_t)(b0 + r) * 64 + (kc - 32) * 8];
      float4 x0 = p[0], x1 = p[1];
      v[0] = x0.x; v[1] = x0.y; v[2] = x0.z; v[3] = x0.w;
      v[4] = x1.x; v[5] = x1.y; v[6] = x1.z; v[7] = x1.w;
    } else if (kc < 48) {
      const float4* p = (const float4*)&qd[(size_t)(b0 + r) * 64 + (kc - 40) * 8];
      float4 x0 = p[0], x1 = p[1];
      v[0] = x0.x; v[1] = x0.y; v[2] = x0.z; v[3] = x0.w;
      v[4] = x1.x; v[5] = x1.y; v[6] = x1.z; v[7] = x1.w;
    } else if (kc == 48) {
      #pragma unroll
      for (int j = 0; j < 8; ++j) v[j] = (j < 4) ? qv[(size_t)(b0 + r) * 4 + j] : 0.0f;
    } else {
      #pragma unroll
      for (int j = 0; j < 8; ++j) v[j] = 0.0f;
    }
    int kt = kc >> 2;
    int lane = rr + (kc & 3) * 16;
    uint4 wq;
    wq.x = pk2(v[0], v[1]); wq.y = pk2(v[2], v[3]);
    wq.z = pk2(v[4], v[5]); wq.w = pk2(v[6], v[7]);
    *(uint4*)&As[kt][mf][lane][0] = wq;
  }
  __syncthreads();

  const int colb = wv * 64 + (l & 15);     // + ntl*16
  const int rowb = (l >> 4) * 4;           // + mf*16 + r

  #pragma unroll
  for (int mat = 0; mat < 4; ++mat) {
    const int ktN  = (mat == 2) ? 8 : (mat == 3) ? 9 : 10;
    const int ktB  = mat == 0 ? 0 : mat == 1 ? 160 : mat == 2 ? 320 : 448;
    const float* bv = mat == 0 ? bij : mat == 1 ? bid : mat == 2 ? bgj : bgd;
    f32x4 acc[2][4];
    #pragma unroll
    for (int ntl = 0; ntl < 4; ++ntl) {
      float bb = bv[colb + ntl * 16];
      f32x4 s = {bb, bb, bb, bb};
      acc[0][ntl] = s; acc[1][ntl] = s;
    }
    #pragma unroll
    for (int kk = 0; kk < ktN; ++kk) {
      int ktA = (kk < 8) ? kk : (mat == 0 ? kk : mat == 1 ? kk + 2 : 12);
      bf16x8 a0 = *(const bf16x8*)&As[ktA][0][l][0];
      bf16x8 a1 = *(const bf16x8*)&As[ktA][1][l][0];
      #pragma unroll
      for (int ntl = 0; ntl < 4; ++ntl) {
        bf16x8 bf = *(const bf16x8*)&sBs[((size_t)(ktB + kk * 16 + wv * 4 + ntl) * 64 + l) * 8];
        acc[0][ntl] = MFMA(a0, bf, acc[0][ntl]);
        acc[1][ntl] = MFMA(a1, bf, acc[1][ntl]);
      }
    }
    float* dp = pre + (size_t)mat * B * 256;
    #pragma unroll
    for (int mf = 0; mf < 2; ++mf)
      #pragma unroll
      for (int ntl = 0; ntl < 4; ++ntl)
        #pragma unroll
        for (int r = 0; r < 4; ++r)
          dp[(size_t)(b0 + mf * 16 + rowb + r) * 256 + colb + ntl * 16] = acc[mf][ntl][r];
  }
}

// ============ Kernel 3: MFMA recurrence (4 barriers/step) ==================
// A-frag: lane l holds A[row=l&15][k=(l>>4)*8+j].
// fr bufs: 0,1 = hi double-buf; 2 = hg; 3 = z; 4,5 = u double-buf.

#define WR_FR(buf, row, c, v) \
  fr[buf][(c) >> 5][((row) & 15) + (((c) >> 3) & 3) * 16][(c) & 7] = f2bf(v)
#define LD_FR(buf, kt) (*(const bf16x8*)&fr[buf][kt][l][0])
#define LD_B(off, kt, nt, NT) \
  (*(const bf16x8*)(FB + (off) + (((kt) * (NT) + (nt)) * 64 + l) * 8))
#define LD_H(ph, kt, nt) \
  (*(const bf16x8*)&shH[(ph) * 8192 + (((kt) * 8 + (nt)) * 64 + l) * 8])

__global__ __launch_bounds__(256, 2) void GeRN_recur(
    const unsigned short* __restrict__ frB,
    const float* __restrict__ pre_ij, const float* __restrict__ pre_id,
    const float* __restrict__ pre_gj, const float* __restrict__ pre_gd,
    const float* __restrict__ bprj, const float* __restrict__ bprd,
    const float* __restrict__ bpoj, const float* __restrict__ bpod,
    const float* __restrict__ bdj,  const float* __restrict__ bdd,
    const float* __restrict__ hi_j0, const float* __restrict__ ci_j0,
    const float* __restrict__ hi_d0, const float* __restrict__ ci_d0,
    const float* __restrict__ hg_j0, const float* __restrict__ cg_j0,
    const float* __restrict__ hg_d0, const float* __restrict__ cg_d0,
    const float* __restrict__ ug_j0, const float* __restrict__ ug_d0,
    float* __restrict__ out, int B, int nd)
{
  alignas(16) __shared__ unsigned short fr[6][2][64][8];     // 12 KB
  alignas(16) __shared__ float preL[2][4][4][64][4];         // 32 KB
  alignas(16) __shared__ unsigned short shH[16384];          // 32 KB (WPR|WPO)

  const int tid = threadIdx.x;
  const int l   = tid & 63;
  const int wv  = tid >> 6;        // wave 0..3 (column slice)
  const int s   = blockIdx.x & 1;  // 0=j, 1=d
  const int rbk = blockIdx.x >> 1;
  const int r0  = (l >> 4) * 4;
  const int col = wv * 16 + (l & 15);
  const int bbase = rbk * 16;
  const size_t BN = (size_t)B * 64;

  const float* hi0 = s ? hi_d0 : hi_j0;  const float* ci0 = s ? ci_d0 : ci_j0;
  const float* hg0 = s ? hg_d0 : hg_j0;  const float* cg0 = s ? cg_d0 : cg_j0;
  const float* ug0 = s ? ug_d0 : ug_j0;
  const float* preIg = s ? pre_id : pre_ij;
  const float* preGg = s ? pre_gd : pre_gj;
  const float* BPR = s ? bprd : bprj;
  const float* BPO = s ? bpod : bpoj;
  const float* BD  = s ? bdd  : bdj;
  const unsigned short* FB = frB + (size_t)s * FR_SIDE;

  // ---- persistent B-fragments in registers ----
  bf16x8 wi[4][4], wg[4][4], wd[4];
  #pragma unroll
  for (int kt = 0; kt < 4; ++kt) {
    #pragma unroll
    for (int g = 0; g < 4; ++g) {
      wi[kt][g] = LD_B(FR_WI, kt, g * 4 + wv, 16);
      wg[kt][g] = LD_B(FR_WG, kt, g * 4 + wv, 16);
    }
    wd[kt] = LD_B(FR_WD, kt, wv, 4);
  }
  // ---- WPR|WPO -> LDS ----
  {
    const float4* src = (const float4*)(FB + FR_WPR);
    float4* dst = (float4*)shH;
    for (int i = tid; i < 2048; i += 256) dst[i] = src[i];
  }

  // ---- states ----
  float hi_[4], ci_[4], hg_[4], cg_[4], u_[4];
  #pragma unroll
  for (int r = 0; r < 4; ++r) {
    size_t gi = (size_t)(bbase + r0 + r) * 64 + col;
    hi_[r] = hi0[gi]; ci_[r] = ci0[gi];
    hg_[r] = hg0[gi]; cg_[r] = cg0[gi];
    u_[r]  = ug0[gi];
  }
  const float bprm = BPR[col], bprv = BPR[64 + col];
  const float bpom = BPO[col], bpov = BPO[64 + col];
  const float bd   = BD[col];

  #pragma unroll
  for (int g = 0; g < 4; ++g)
    #pragma unroll
    for (int r = 0; r < 4; ++r) {
      preL[0][g][wv][l][r] = preIg[(size_t)(bbase + r0 + r) * 256 + g * 64 + col];
      preL[1][g][wv][l][r] = preGg[(size_t)(bbase + r0 + r) * 256 + g * 64 + col];
    }
  #pragma unroll
  for (int r = 0; r < 4; ++r) {
    WR_FR(0, r0 + r, col, hi_[r]);   // hi -> H0
    WR_FR(2, r0 + r, col, hg_[r]);
    WR_FR(4, r0 + r, col, u_[r]);    // u -> U0
  }
  __syncthreads();

  const float zo = s ? 0.2f : 0.3f, zo1 = 1.0f - zo;

  // ---- hoisted output pointers & eps counter ----
  const unsigned gi0 = (unsigned)((bbase + r0) * 64 + col);
  float* o_prm = out + (size_t)(2 + (2 * s) * nd) * BN + gi0;
  float* o_prv = out + (size_t)(2 + (2 * s + 1) * nd) * BN + gi0;
  float* o_pom = out + (size_t)(2 + (4 + 2 * s) * nd) * BN + gi0;
  float* o_pov = out + (size_t)(2 + (5 + 2 * s) * nd) * BN + gi0;
  unsigned e0 = gi0;
  const unsigned BNu = (unsigned)BN;
  const unsigned eseed = 1u + (unsigned)s;

  for (int t = 0; t < nd; ++t) {
    const int cb = t & 1;
    // ---- P1: A-frags of hg_old, hi_old (no barrier: dbl-buffered hi) ----
    bf16x8 a_hg0 = LD_FR(2, 0), a_hg1 = LD_FR(2, 1);
    bf16x8 a_hi0 = LD_FR(cb, 0), a_hi1 = LD_FR(cb, 1);

    // ---- P2: prior head + inference LSTM ----
    {
      f32x4 am = {bprm, bprm, bprm, bprm};
      f32x4 av = {bprv, bprv, bprv, bprv};
      am = MFMA(a_hg0, LD_H(0, 0, wv), am);
      am = MFMA(a_hg1, LD_H(0, 1, wv), am);
      av = MFMA(a_hg0, LD_H(0, 0, wv + 4), av);
      av = MFMA(a_hg1, LD_H(0, 1, wv + 4), av);
      #pragma unroll
      for (int r = 0; r < 4; ++r) {
        o_prm[r * 64] = am[r];
        o_prv[r * 64] = av[r];
      }
    }
    {
      f32x4 acc[4];
      #pragma unroll
      for (int g = 0; g < 4; ++g) acc[g] = *(const f32x4*)&preL[0][g][wv][l][0];
      #pragma unroll
      for (int g = 0; g < 4; ++g) {
        acc[g] = MFMA(a_hg0, wi[0][g], acc[g]);
        acc[g] = MFMA(a_hg1, wi[1][g], acc[g]);
        acc[g] = MFMA(a_hi0, wi[2][g], acc[g]);
        acc[g] = MFMA(a_hi1, wi[3][g], acc[g]);
      }
      #pragma unroll
      for (int r = 0; r < 4; ++r) {
        float ig = sigf(acc[0][r]), fg = sigf(acc[1][r]);
        float gg = tanh_f(acc[2][r]), og = sigf(acc[3][r]);
        float cn = fmaf(fg, ci_[r], ig * gg);
        float hn = og * tanh_f(cn);
        hi_[r] = fmaf(zo, hi_[r], zo1 * hn);
        ci_[r] = fmaf(zo, ci_[r], zo1 * cn);
        WR_FR(cb ^ 1, r0 + r, col, hi_[r]);   // new hi -> other buffer
      }
    }
    __syncthreads();                                 // B2

    // ---- P3: posterior head + z sample ----
    {
      bf16x8 a0 = LD_FR(cb ^ 1, 0), a1 = LD_FR(cb ^ 1, 1);
      f32x4 am = {bpom, bpom, bpom, bpom};
      f32x4 av = {bpov, bpov, bpov, bpov};
      am = MFMA(a0, LD_H(1, 0, wv), am);
      am = MFMA(a1, LD_H(1, 1, wv), am);
      av = MFMA(a0, LD_H(1, 0, wv + 4), av);
      av = MFMA(a1, LD_H(1, 1, wv + 4), av);
      #pragma unroll
      for (int r = 0; r < 4; ++r) {
        o_pom[r * 64] = am[r];
        o_pov[r * 64] = av[r];
        float e = eps_threefry(eseed, e0 + r * 64);
        float z = fmaf(__expf(0.5f * av[r]), e, am[r]);
        WR_FR(3, r0 + r, col, z);
      }
    }
    __syncthreads();                                 // B3

    // ---- P4: generator LSTM (x1 = z, x2 = hg_old) ----
    {
      bf16x8 az0 = LD_FR(3, 0), az1 = LD_FR(3, 1);
      f32x4 acc[4];
      #pragma unroll
      for (int g = 0; g < 4; ++g) acc[g] = *(const f32x4*)&preL[1][g][wv][l][0];
      #pragma unroll
      for (int g = 0; g < 4; ++g) {
        acc[g] = MFMA(az0,   wg[0][g], acc[g]);
        acc[g] = MFMA(az1,   wg[1][g], acc[g]);
        acc[g] = MFMA(a_hg0, wg[2][g], acc[g]);
        acc[g] = MFMA(a_hg1, wg[3][g], acc[g]);
      }
      #pragma unroll
      for (int r = 0; r < 4; ++r) {
        float ig = sigf(acc[0][r]), fg = sigf(acc[1][r]);
        float gg = tanh_f(acc[2][r]), og = sigf(acc[3][r]);
        float cn = fmaf(fg, cg_[r], ig * gg);
        float hn = og * tanh_f(cn);
        hg_[r] = fmaf(zo, hg_[r], zo1 * hn);
        cg_[r] = fmaf(zo, cg_[r], zo1 * cn);
        WR_FR(2, r0 + r, col, hg_[r]);
      }
    }
    __syncthreads();                                 // B4

    // ---- P5: canvas delta u += leaky(Wd @ [u, hg_new] + b) ----
    {
      bf16x8 au0 = LD_FR(4 + cb, 0), au1 = LD_FR(4 + cb, 1);
      bf16x8 ah0 = LD_FR(2, 0), ah1 = LD_FR(2, 1);
      f32x4 acc = {bd, bd, bd, bd};
      acc = MFMA(au0, wd[0], acc);
      acc = MFMA(au1, wd[1], acc);
      acc = MFMA(ah0, wd[2], acc);
      acc = MFMA(ah1, wd[3], acc);
      #pragma unroll
      for (int r = 0; r < 4; ++r) {
        float a = acc[r];
        float d = a > 0.0f ? a : 0.01f * a;
        u_[r] += d;
        WR_FR(4 + (cb ^ 1), r0 + r, col, u_[r]);   // new u -> other buffer
      }
    }
    __syncthreads();                                 // B6

    o_prm += BN; o_prv += BN; o_pom += BN; o_pov += BN;
    e0 += BNu;
  }

  // ---- final canvases ----
  #pragma unroll
  for (int r = 0; r < 4; ++r) {
    size_t gi = (size_t)(bbase + r0 + r) * 64 + col;
    out[(size_t)s * BN + gi] = u_[r];
  }
}

extern "C" void kernel_launch(void* const* d_in, const int* in_sizes, int n_in,
                              void* d_out, int out_size, void* d_ws, size_t ws_size,
                              hipStream_t stream)
{
  const float* cnd = (const float*)d_in[1];
  const float* qj  = (const float*)d_in[2];
  const float* qd  = (const float*)d_in[3];
  const float* qv  = (const float*)d_in[4];
  const float* hi_j0 = (const float*)d_in[5];
  const float* ci_j0 = (const float*)d_in[6];
  const float* hi_d0 = (const float*)d_in[8];
  const float* ci_d0 = (const float*)d_in[9];
  const float* hg_j0 = (const float*)d_in[11];
  const float* cg_j0 = (const float*)d_in[12];
  const float* hg_d0 = (const float*)d_in[14];
  const float* cg_d0 = (const float*)d_in[15];
  const float* ug_j0 = (const float*)d_in[17];
  const float* ug_d0 = (const float*)d_in[18];
  const float* Wij = (const float*)d_in[19]; const float* bij = (const float*)d_in[20];
  const float* Wid = (const float*)d_in[21]; const float* bid = (const float*)d_in[22];
  const float* Wgj = (const float*)d_in[23]; const float* bgj = (const float*)d_in[24];
  const float* Wgd = (const float*)d_in[25]; const float* bgd = (const float*)d_in[26];
  const float* Wpoj = (const float*)d_in[27]; const float* bpoj = (const float*)d_in[28];
  const float* Wpod = (const float*)d_in[29]; const float* bpod = (const float*)d_in[30];
  const float* Wprj = (const float*)d_in[31]; const float* bprj = (const float*)d_in[32];
  const float* Wprd = (const float*)d_in[33]; const float* bprd = (const float*)d_in[34];
  const float* Wdj = (const float*)d_in[35]; const float* bdj = (const float*)d_in[36];
  const float* Wdd = (const float*)d_in[37]; const float* bdd = (const float*)d_in[38];

  const int B = in_sizes[1] / 256;                 // cnd_repr is [B,256]
  const int slots = out_size / (B * 64);           // 2 + 8*ndraw
  const int nd = (slots - 2) / 8;

  float* ws = (float*)d_ws;                        // pre: 4*B*256 f32 (32 MB)
  unsigned short* frB = (unsigned short*)(ws + (size_t)4 * B * 256);
  unsigned short* sBs = frB + 2 * FR_SIDE;         // 592 KB static B-frags
  float* out = (float*)d_out;

  GeRN_prep<<<944, 64, 0, stream>>>(
      Wij, Wid, Wgj, Wgd, Wprj, Wprd, Wpoj, Wpod, Wdj, Wdd, frB, sBs);
  GeRN_staticM<<<B / 32, 256, 0, stream>>>(
      cnd, qj, qd, qv, bij, bid, bgj, bgd, sBs, ws, B);
  GeRN_recur<<<2 * (B / 16), 256, 0, stream>>>(
      frB,
      ws, ws + (size_t)B * 256, ws + (size_t)2 * B * 256, ws + (size_t)3 * B * 256,
      bprj, bprd, bpoj, bpod, bdj, bdd,
      hi_j0, ci_j0, hi_d0, ci_d0, hg_j0, cg_j0, hg_d0, cg_d0, ug_j0, ug_d0,
      out, B, nd);
}

// Round 7
// 232.047 us; speedup vs baseline: 269.4183x; 1.0321x over previous
//
#include <hip/hip_runtime.h>
#include <hip/hip_bf16.h>

// GeRN fused, round 7:
//  GeRN_prep   : weights -> bf16 B-frag layout (dynamic frB + static sBs).
//  GeRN_staticM: static gate pre-activations via MFMA.
//  GeRN_eps    : ALL threefry/erfinv eps values precomputed to ws (f32).
//  GeRN_recur<USE_EPS>: MFMA recurrence; <1> loads eps (4 coalesced loads)
//    instead of ~440 VALU inst of inline RNG per thread-step.

#define RROWS 16

typedef __attribute__((ext_vector_type(8))) short bf16x8;
typedef __attribute__((ext_vector_type(4))) float f32x4;

#define MFMA(A, Bv, C) __builtin_amdgcn_mfma_f32_16x16x32_bf16(A, Bv, C, 0, 0, 0)

// frag-buffer element offsets (unsigned short units), per side
#define FR_WI   0
#define FR_WG   32768
#define FR_WPR  65536
#define FR_WPO  73728
#define FR_WD   81920
#define FR_SIDE 90112   // per side

__device__ __forceinline__ unsigned short f2bf(float f) {
  unsigned u = __float_as_uint(f);
  return (unsigned short)((u + 0x7FFFu + ((u >> 16) & 1u)) >> 16);
}
__device__ __forceinline__ unsigned pk2(float a, float b) {
  return (unsigned)f2bf(a) | ((unsigned)f2bf(b) << 16);
}
__device__ __forceinline__ float sigf(float x) {
  return 1.0f / (1.0f + __expf(-x));
}
__device__ __forceinline__ float tanh_f(float x) {
  return 1.0f - 2.0f / (__expf(2.0f * x) + 1.0f);
}

// --- JAX threefry2x32-20 (partitionable) + uniform + XLA ErfInv32 ---
__device__ __forceinline__ float eps_threefry(unsigned seed, unsigned idx) {
  unsigned x0 = 0u, x1 = idx;
  const unsigned ks0 = 0u, ks1 = seed, ks2 = seed ^ 0x1BD11BDAu;
  x0 += ks0; x1 += ks1;
#define TF_R(r) { x0 += x1; x1 = (x1 << (r)) | (x1 >> (32 - (r))); x1 ^= x0; }
  TF_R(13) TF_R(15) TF_R(26) TF_R(6)  x0 += ks1; x1 += ks2 + 1u;
  TF_R(17) TF_R(29) TF_R(16) TF_R(24) x0 += ks2; x1 += ks0 + 2u;
  TF_R(13) TF_R(15) TF_R(26) TF_R(6)  x0 += ks0; x1 += ks1 + 3u;
  TF_R(17) TF_R(29) TF_R(16) TF_R(24) x0 += ks1; x1 += ks2 + 4u;
  TF_R(13) TF_R(15) TF_R(26) TF_R(6)  x0 += ks2; x1 += ks0 + 5u;
#undef TF_R
  unsigned bits = x0 ^ x1;
  unsigned fb = (bits >> 9) | 0x3F800000u;
  const float lo = -0.99999994f;
  float f = __uint_as_float(fb) - 1.0f;
  float u = fmaxf(lo, f * 2.0f + lo);
  float w = -log1pf(-u * u);
  float p;
  if (w < 5.0f) {
    w -= 2.5f;
    p = 2.81022636e-08f;
    p = fmaf(p, w, 3.43273939e-07f);
    p = fmaf(p, w, -3.5233877e-06f);
    p = fmaf(p, w, -4.39150654e-06f);
    p = fmaf(p, w, 0.00021858087f);
    p = fmaf(p, w, -0.00125372503f);
    p = fmaf(p, w, -0.00417768164f);
    p = fmaf(p, w, 0.246640727f);
    p = fmaf(p, w, 1.50140941f);
  } else {
    w = sqrtf(w) - 3.0f;
    p = -0.000200214257f;
    p = fmaf(p, w, 0.000100950558f);
    p = fmaf(p, w, 0.00134934322f);
    p = fmaf(p, w, -0.00367342844f);
    p = fmaf(p, w, 0.00573950773f);
    p = fmaf(p, w, -0.0076224613f);
    p = fmaf(p, w, 0.00943887047f);
    p = fmaf(p, w, 1.00167406f);
    p = fmaf(p, w, 2.83297682f);
  }
  return 1.41421356f * (p * u);
}

// ============ Kernel 0: eps precompute =====================================
__global__ __launch_bounds__(256) void GeRN_eps(float* __restrict__ ebuf,
                                                unsigned ndBN)
{
  unsigned j0 = (blockIdx.x * 256u + threadIdx.x) * 8u;
  const unsigned total = 2u * ndBN;
  if (j0 >= total) return;
  const unsigned s = (j0 >= ndBN) ? 1u : 0u;
  const unsigned i0 = j0 - s * ndBN;
  const unsigned seed = 1u + s;
  float v[8];
  #pragma unroll
  for (int k = 0; k < 8; ++k) v[k] = eps_threefry(seed, i0 + (unsigned)k);
  float4 a = {v[0], v[1], v[2], v[3]};
  float4 b = {v[4], v[5], v[6], v[7]};
  *(float4*)(ebuf + j0) = a;
  *(float4*)(ebuf + j0 + 4) = b;
}

// ============ Kernel 1: prep — all weights to bf16 B-frag layout ===========
// B-frag (16x16x32): lane l holds B[k=(l>>4)*8+j][n=l&15], j contiguous.
__global__ __launch_bounds__(64) void GeRN_prep(
    const float* __restrict__ Wij, const float* __restrict__ Wid,
    const float* __restrict__ Wgj, const float* __restrict__ Wgd,
    const float* __restrict__ Wprj, const float* __restrict__ Wprd,
    const float* __restrict__ Wpoj, const float* __restrict__ Wpod,
    const float* __restrict__ Wdj, const float* __restrict__ Wdd,
    unsigned short* __restrict__ frB, unsigned short* __restrict__ sBs)
{
  const int l = threadIdx.x;
  if (blockIdx.x < 352) {
    const int s = blockIdx.x / 176;
    int tt = blockIdx.x % 176;
    const float* W; int ldw, rb, NT, kt, nt; size_t doff;
    if (tt < 64)       { W = s ? Wid : Wij; ldw = 256; NT = 16; kt = tt >> 4; nt = tt & 15;
                         rb = 320 + kt * 32; doff = FR_WI; }
    else if (tt < 128) { tt -= 64; W = s ? Wgd : Wgj; ldw = 256; NT = 16; kt = tt >> 4; nt = tt & 15;
                         rb = (kt < 2) ? 256 + kt * 32 : (s ? 324 : 320) + (kt - 2) * 32; doff = FR_WG; }
    else if (tt < 144) { tt -= 128; W = s ? Wprd : Wprj; ldw = 128; NT = 8; kt = tt >> 3; nt = tt & 7;
                         rb = kt * 32; doff = FR_WPR; }
    else if (tt < 160) { tt -= 144; W = s ? Wpod : Wpoj; ldw = 128; NT = 8; kt = tt >> 3; nt = tt & 7;
                         rb = kt * 32; doff = FR_WPO; }
    else               { tt -= 160; W = s ? Wdd : Wdj; ldw = 64; NT = 4; kt = tt >> 2; nt = tt & 3;
                         rb = (kt < 2) ? kt * 32 : 64 + (kt - 2) * 32; doff = FR_WD; }
    unsigned short* dst = frB + (size_t)s * FR_SIDE + doff
                        + ((size_t)(kt * NT + nt) * 64 + l) * 8;
    const int kk = (l >> 4) * 8;
    const int c = nt * 16 + (l & 15);
    #pragma unroll
    for (int j = 0; j < 8; ++j)
      dst[j] = f2bf(W[(size_t)(rb + kk + j) * ldw + c]);
  } else {
    int bb = blockIdx.x - 352;        // tile id 0..591
    int mat, base;
    if (bb < 160)      { mat = 0; base = 0; }
    else if (bb < 320) { mat = 1; base = 160; }
    else if (bb < 448) { mat = 2; base = 320; }
    else               { mat = 3; base = 448; }
    int tt = bb - base;
    int kk = tt >> 4, nt = tt & 15;
    const float* W = mat == 0 ? Wij : mat == 1 ? Wid : mat == 2 ? Wgj : Wgd;
    const int c = nt * 16 + (l & 15);
    const int kl0 = (l >> 4) * 8;
    unsigned short* dst = sBs + ((size_t)bb * 64 + l) * 8;
    if (mat == 3 && kk == 8) {          // qv rows 320..323 + zero pad
      #pragma unroll
      for (int j = 0; j < 8; ++j) {
        int klo = kl0 + j;
        dst[j] = (klo < 4) ? f2bf(W[(size_t)(320 + klo) * 256 + c]) : (unsigned short)0;
      }
    } else {
      int rb = (kk < 8) ? kk * 32 : 256 + (kk - 8) * 32;
      #pragma unroll
      for (int j = 0; j < 8; ++j)
        dst[j] = f2bf(W[(size_t)(rb + kl0 + j) * 256 + c]);
    }
  }
}

// ============ Kernel 2: static pre-activations via MFMA ====================
__global__ __launch_bounds__(256) void GeRN_staticM(
    const float* __restrict__ cnd, const float* __restrict__ qj,
    const float* __restrict__ qd, const float* __restrict__ qv,
    const float* __restrict__ bij, const float* __restrict__ bid,
    const float* __restrict__ bgj, const float* __restrict__ bgd,
    const unsigned short* __restrict__ sBs,
    float* __restrict__ pre, int B)
{
  alignas(16) __shared__ unsigned short As[13][2][64][8];   // 26 KB
  const int tid = threadIdx.x;
  const int l = tid & 63;
  const int wv = tid >> 6;
  const int b0 = blockIdx.x * 32;

  for (int i = tid; i < 32 * 52; i += 256) {
    int r = i / 52, kc = i % 52;
    int mf = r >> 4, rr = r & 15;
    float v[8];
    if (kc < 32) {
      const float4* p = (const float4*)&cnd[(size_t)(b0 + r) * 256 + kc * 8];
      float4 x0 = p[0], x1 = p[1];
      v[0] = x0.x; v[1] = x0.y; v[2] = x0.z; v[3] = x0.w;
      v[4] = x1.x; v[5] = x1.y; v[6] = x1.z; v[7] = x1.w;
    } else if (kc < 40) {
      const float4* p = (const float4*)&qj[(size_t)(b0 + r) * 64 + (kc - 32) * 8];
      float4 x0 = p[0], x1 = p[1];
      v[0] = x0.x; v[1] = x0.y; v[2] = x0.z; v[3] = x0.w;
      v[4] = x1.x; v[5] = x1.y; v[6] = x1.z; v[7] = x1.w;
    } else if (kc < 48) {
      const float4* p = (const float4*)&qd[(size_t)(b0 + r) * 64 + (kc - 40) * 8];
      float4 x0 = p[0], x1 = p[1];
      v[0] = x0.x; v[1] = x0.y; v[2] = x0.z; v[3] = x0.w;
      v[4] = x1.x; v[5] = x1.y; v[6] = x1.z; v[7] = x1.w;
    } else if (kc == 48) {
      #pragma unroll
      for (int j = 0; j < 8; ++j) v[j] = (j < 4) ? qv[(size_t)(b0 + r) * 4 + j] : 0.0f;
    } else {
      #pragma unroll
      for (int j = 0; j < 8; ++j) v[j] = 0.0f;
    }
    int kt = kc >> 2;
    int lane = rr + (kc & 3) * 16;
    uint4 wq;
    wq.x = pk2(v[0], v[1]); wq.y = pk2(v[2], v[3]);
    wq.z = pk2(v[4], v[5]); wq.w = pk2(v[6], v[7]);
    *(uint4*)&As[kt][mf][lane][0] = wq;
  }
  __syncthreads();

  const int colb = wv * 64 + (l & 15);
  const int rowb = (l >> 4) * 4;

  #pragma unroll
  for (int mat = 0; mat < 4; ++mat) {
    const int ktN  = (mat == 2) ? 8 : (mat == 3) ? 9 : 10;
    const int ktB  = mat == 0 ? 0 : mat == 1 ? 160 : mat == 2 ? 320 : 448;
    const float* bv = mat == 0 ? bij : mat == 1 ? bid : mat == 2 ? bgj : bgd;
    f32x4 acc[2][4];
    #pragma unroll
    for (int ntl = 0; ntl < 4; ++ntl) {
      float bb = bv[colb + ntl * 16];
      f32x4 s = {bb, bb, bb, bb};
      acc[0][ntl] = s; acc[1][ntl] = s;
    }
    #pragma unroll
    for (int kk = 0; kk < ktN; ++kk) {
      int ktA = (kk < 8) ? kk : (mat == 0 ? kk : mat == 1 ? kk + 2 : 12);
      bf16x8 a0 = *(const bf16x8*)&As[ktA][0][l][0];
      bf16x8 a1 = *(const bf16x8*)&As[ktA][1][l][0];
      #pragma unroll
      for (int ntl = 0; ntl < 4; ++ntl) {
        bf16x8 bf = *(const bf16x8*)&sBs[((size_t)(ktB + kk * 16 + wv * 4 + ntl) * 64 + l) * 8];
        acc[0][ntl] = MFMA(a0, bf, acc[0][ntl]);
        acc[1][ntl] = MFMA(a1, bf, acc[1][ntl]);
      }
    }
    float* dp = pre + (size_t)mat * B * 256;
    #pragma unroll
    for (int mf = 0; mf < 2; ++mf)
      #pragma unroll
      for (int ntl = 0; ntl < 4; ++ntl)
        #pragma unroll
        for (int r = 0; r < 4; ++r)
          dp[(size_t)(b0 + mf * 16 + rowb + r) * 256 + colb + ntl * 16] = acc[mf][ntl][r];
  }
}

// ============ Kernel 3: MFMA recurrence (4 barriers/step) ==================
#define WR_FR(buf, row, c, v) \
  fr[buf][(c) >> 5][((row) & 15) + (((c) >> 3) & 3) * 16][(c) & 7] = f2bf(v)
#define LD_FR(buf, kt) (*(const bf16x8*)&fr[buf][kt][l][0])
#define LD_B(off, kt, nt, NT) \
  (*(const bf16x8*)(FB + (off) + (((kt) * (NT) + (nt)) * 64 + l) * 8))
#define LD_H(ph, kt, nt) \
  (*(const bf16x8*)&shH[(ph) * 8192 + (((kt) * 8 + (nt)) * 64 + l) * 8])

template<int USE_EPS>
__global__ __launch_bounds__(256, 2) void GeRN_recur(
    const unsigned short* __restrict__ frB,
    const float* __restrict__ pre_ij, const float* __restrict__ pre_id,
    const float* __restrict__ pre_gj, const float* __restrict__ pre_gd,
    const float* __restrict__ bprj, const float* __restrict__ bprd,
    const float* __restrict__ bpoj, const float* __restrict__ bpod,
    const float* __restrict__ bdj,  const float* __restrict__ bdd,
    const float* __restrict__ hi_j0, const float* __restrict__ ci_j0,
    const float* __restrict__ hi_d0, const float* __restrict__ ci_d0,
    const float* __restrict__ hg_j0, const float* __restrict__ cg_j0,
    const float* __restrict__ hg_d0, const float* __restrict__ cg_d0,
    const float* __restrict__ ug_j0, const float* __restrict__ ug_d0,
    const float* __restrict__ eps_buf, unsigned ndBN,
    float* __restrict__ out, int B, int nd)
{
  alignas(16) __shared__ unsigned short fr[6][2][64][8];     // 12 KB
  alignas(16) __shared__ float preL[2][4][4][64][4];         // 32 KB
  alignas(16) __shared__ unsigned short shH[16384];          // 32 KB (WPR|WPO)

  const int tid = threadIdx.x;
  const int l   = tid & 63;
  const int wv  = tid >> 6;
  const int s   = blockIdx.x & 1;  // 0=j, 1=d
  const int rbk = blockIdx.x >> 1;
  const int r0  = (l >> 4) * 4;
  const int col = wv * 16 + (l & 15);
  const int bbase = rbk * 16;
  const size_t BN = (size_t)B * 64;

  const float* hi0 = s ? hi_d0 : hi_j0;  const float* ci0 = s ? ci_d0 : ci_j0;
  const float* hg0 = s ? hg_d0 : hg_j0;  const float* cg0 = s ? cg_d0 : cg_j0;
  const float* ug0 = s ? ug_d0 : ug_j0;
  const float* preIg = s ? pre_id : pre_ij;
  const float* preGg = s ? pre_gd : pre_gj;
  const float* BPR = s ? bprd : bprj;
  const float* BPO = s ? bpod : bpoj;
  const float* BD  = s ? bdd  : bdj;
  const unsigned short* FB = frB + (size_t)s * FR_SIDE;

  // ---- persistent B-fragments in registers ----
  bf16x8 wi[4][4], wg[4][4], wd[4];
  #pragma unroll
  for (int kt = 0; kt < 4; ++kt) {
    #pragma unroll
    for (int g = 0; g < 4; ++g) {
      wi[kt][g] = LD_B(FR_WI, kt, g * 4 + wv, 16);
      wg[kt][g] = LD_B(FR_WG, kt, g * 4 + wv, 16);
    }
    wd[kt] = LD_B(FR_WD, kt, wv, 4);
  }
  // ---- WPR|WPO -> LDS ----
  {
    const float4* src = (const float4*)(FB + FR_WPR);
    float4* dst = (float4*)shH;
    for (int i = tid; i < 2048; i += 256) dst[i] = src[i];
  }

  // ---- states ----
  float hi_[4], ci_[4], hg_[4], cg_[4], u_[4];
  #pragma unroll
  for (int r = 0; r < 4; ++r) {
    size_t gi = (size_t)(bbase + r0 + r) * 64 + col;
    hi_[r] = hi0[gi]; ci_[r] = ci0[gi];
    hg_[r] = hg0[gi]; cg_[r] = cg0[gi];
    u_[r]  = ug0[gi];
  }
  const float bprm = BPR[col], bprv = BPR[64 + col];
  const float bpom = BPO[col], bpov = BPO[64 + col];
  const float bd   = BD[col];

  #pragma unroll
  for (int g = 0; g < 4; ++g)
    #pragma unroll
    for (int r = 0; r < 4; ++r) {
      preL[0][g][wv][l][r] = preIg[(size_t)(bbase + r0 + r) * 256 + g * 64 + col];
      preL[1][g][wv][l][r] = preGg[(size_t)(bbase + r0 + r) * 256 + g * 64 + col];
    }
  #pragma unroll
  for (int r = 0; r < 4; ++r) {
    WR_FR(0, r0 + r, col, hi_[r]);   // hi -> H0
    WR_FR(2, r0 + r, col, hg_[r]);
    WR_FR(4, r0 + r, col, u_[r]);    // u -> U0
  }
  __syncthreads();

  const float zo = s ? 0.2f : 0.3f, zo1 = 1.0f - zo;

  // ---- hoisted output pointers & eps stream ----
  const unsigned gi0 = (unsigned)((bbase + r0) * 64 + col);
  float* o_prm = out + (size_t)(2 + (2 * s) * nd) * BN + gi0;
  float* o_prv = out + (size_t)(2 + (2 * s + 1) * nd) * BN + gi0;
  float* o_pom = out + (size_t)(2 + (4 + 2 * s) * nd) * BN + gi0;
  float* o_pov = out + (size_t)(2 + (5 + 2 * s) * nd) * BN + gi0;
  unsigned e0 = gi0;
  const unsigned BNu = (unsigned)BN;
  const unsigned eseed = 1u + (unsigned)s;
  const float* ep = USE_EPS ? (eps_buf + (size_t)s * ndBN + gi0) : (const float*)0;

  for (int t = 0; t < nd; ++t) {
    const int cb = t & 1;
    // ---- eps prefetch (used in P3, ~2 phases away) ----
    float epre[4];
    if (USE_EPS) {
      #pragma unroll
      for (int r = 0; r < 4; ++r) epre[r] = ep[r * 64];
    }
    // ---- P1: A-frags of hg_old, hi_old ----
    bf16x8 a_hg0 = LD_FR(2, 0), a_hg1 = LD_FR(2, 1);
    bf16x8 a_hi0 = LD_FR(cb, 0), a_hi1 = LD_FR(cb, 1);

    // ---- P2: prior head + inference LSTM ----
    {
      f32x4 am = {bprm, bprm, bprm, bprm};
      f32x4 av = {bprv, bprv, bprv, bprv};
      am = MFMA(a_hg0, LD_H(0, 0, wv), am);
      am = MFMA(a_hg1, LD_H(0, 1, wv), am);
      av = MFMA(a_hg0, LD_H(0, 0, wv + 4), av);
      av = MFMA(a_hg1, LD_H(0, 1, wv + 4), av);
      #pragma unroll
      for (int r = 0; r < 4; ++r) {
        o_prm[r * 64] = am[r];
        o_prv[r * 64] = av[r];
      }
    }
    {
      f32x4 acc[4];
      #pragma unroll
      for (int g = 0; g < 4; ++g) acc[g] = *(const f32x4*)&preL[0][g][wv][l][0];
      #pragma unroll
      for (int g = 0; g < 4; ++g) {
        acc[g] = MFMA(a_hg0, wi[0][g], acc[g]);
        acc[g] = MFMA(a_hg1, wi[1][g], acc[g]);
        acc[g] = MFMA(a_hi0, wi[2][g], acc[g]);
        acc[g] = MFMA(a_hi1, wi[3][g], acc[g]);
      }
      #pragma unroll
      for (int r = 0; r < 4; ++r) {
        float ig = sigf(acc[0][r]), fg = sigf(acc[1][r]);
        float gg = tanh_f(acc[2][r]), og = sigf(acc[3][r]);
        float cn = fmaf(fg, ci_[r], ig * gg);
        float hn = og * tanh_f(cn);
        hi_[r] = fmaf(zo, hi_[r], zo1 * hn);
        ci_[r] = fmaf(zo, ci_[r], zo1 * cn);
        WR_FR(cb ^ 1, r0 + r, col, hi_[r]);   // new hi -> other buffer
      }
    }
    __syncthreads();                                 // B2

    // ---- P3: posterior head + z sample ----
    {
      bf16x8 a0 = LD_FR(cb ^ 1, 0), a1 = LD_FR(cb ^ 1, 1);
      f32x4 am = {bpom, bpom, bpom, bpom};
      f32x4 av = {bpov, bpov, bpov, bpov};
      am = MFMA(a0, LD_H(1, 0, wv), am);
      am = MFMA(a1, LD_H(1, 1, wv), am);
      av = MFMA(a0, LD_H(1, 0, wv + 4), av);
      av = MFMA(a1, LD_H(1, 1, wv + 4), av);
      #pragma unroll
      for (int r = 0; r < 4; ++r) {
        o_pom[r * 64] = am[r];
        o_pov[r * 64] = av[r];
        float e = USE_EPS ? epre[r] : eps_threefry(eseed, e0 + r * 64);
        float z = fmaf(__expf(0.5f * av[r]), e, am[r]);
        WR_FR(3, r0 + r, col, z);
      }
    }
    __syncthreads();                                 // B3

    // ---- P4: generator LSTM (x1 = z, x2 = hg_old) ----
    {
      bf16x8 az0 = LD_FR(3, 0), az1 = LD_FR(3, 1);
      f32x4 acc[4];
      #pragma unroll
      for (int g = 0; g < 4; ++g) acc[g] = *(const f32x4*)&preL[1][g][wv][l][0];
      #pragma unroll
      for (int g = 0; g < 4; ++g) {
        acc[g] = MFMA(az0,   wg[0][g], acc[g]);
        acc[g] = MFMA(az1,   wg[1][g], acc[g]);
        acc[g] = MFMA(a_hg0, wg[2][g], acc[g]);
        acc[g] = MFMA(a_hg1, wg[3][g], acc[g]);
      }
      #pragma unroll
      for (int r = 0; r < 4; ++r) {
        float ig = sigf(acc[0][r]), fg = sigf(acc[1][r]);
        float gg = tanh_f(acc[2][r]), og = sigf(acc[3][r]);
        float cn = fmaf(fg, cg_[r], ig * gg);
        float hn = og * tanh_f(cn);
        hg_[r] = fmaf(zo, hg_[r], zo1 * hn);
        cg_[r] = fmaf(zo, cg_[r], zo1 * cn);
        WR_FR(2, r0 + r, col, hg_[r]);
      }
    }
    __syncthreads();                                 // B4

    // ---- P5: canvas delta u += leaky(Wd @ [u, hg_new] + b) ----
    {
      bf16x8 au0 = LD_FR(4 + cb, 0), au1 = LD_FR(4 + cb, 1);
      bf16x8 ah0 = LD_FR(2, 0), ah1 = LD_FR(2, 1);
      f32x4 acc = {bd, bd, bd, bd};
      acc = MFMA(au0, wd[0], acc);
      acc = MFMA(au1, wd[1], acc);
      acc = MFMA(ah0, wd[2], acc);
      acc = MFMA(ah1, wd[3], acc);
      #pragma unroll
      for (int r = 0; r < 4; ++r) {
        float a = acc[r];
        float d = a > 0.0f ? a : 0.01f * a;
        u_[r] += d;
        WR_FR(4 + (cb ^ 1), r0 + r, col, u_[r]);   // new u -> other buffer
      }
    }
    __syncthreads();                                 // B6

    o_prm += BN; o_prv += BN; o_pom += BN; o_pov += BN;
    e0 += BNu;
    if (USE_EPS) ep += BN;
  }

  // ---- final canvases ----
  #pragma unroll
  for (int r = 0; r < 4; ++r) {
    size_t gi = (size_t)(bbase + r0 + r) * 64 + col;
    out[(size_t)s * BN + gi] = u_[r];
  }
}

extern "C" void kernel_launch(void* const* d_in, const int* in_sizes, int n_in,
                              void* d_out, int out_size, void* d_ws, size_t ws_size,
                              hipStream_t stream)
{
  const float* cnd = (const float*)d_in[1];
  const float* qj  = (const float*)d_in[2];
  const float* qd  = (const float*)d_in[3];
  const float* qv  = (const float*)d_in[4];
  const float* hi_j0 = (const float*)d_in[5];
  const float* ci_j0 = (const float*)d_in[6];
  const float* hi_d0 = (const float*)d_in[8];
  const float* ci_d0 = (const float*)d_in[9];
  const float* hg_j0 = (const float*)d_in[11];
  const float* cg_j0 = (const float*)d_in[12];
  const float* hg_d0 = (const float*)d_in[14];
  const float* cg_d0 = (const float*)d_in[15];
  const float* ug_j0 = (const float*)d_in[17];
  const float* ug_d0 = (const float*)d_in[18];
  const float* Wij = (const float*)d_in[19]; const float* bij = (const float*)d_in[20];
  const float* Wid = (const float*)d_in[21]; const float* bid = (const float*)d_in[22];
  const float* Wgj = (const float*)d_in[23]; const float* bgj = (const float*)d_in[24];
  const float* Wgd = (const float*)d_in[25]; const float* bgd = (const float*)d_in[26];
  const float* Wpoj = (const float*)d_in[27]; const float* bpoj = (const float*)d_in[28];
  const float* Wpod = (const float*)d_in[29]; const float* bpod = (const float*)d_in[30];
  const float* Wprj = (const float*)d_in[31]; const float* bprj = (const float*)d_in[32];
  const float* Wprd = (const float*)d_in[33]; const float* bprd = (const float*)d_in[34];
  const float* Wdj = (const float*)d_in[35]; const float* bdj = (const float*)d_in[36];
  const float* Wdd = (const float*)d_in[37]; const float* bdd = (const float*)d_in[38];

  const int B = in_sizes[1] / 256;                 // cnd_repr is [B,256]
  const int slots = out_size / (B * 64);           // 2 + 8*ndraw
  const int nd = (slots - 2) / 8;

  float* ws = (float*)d_ws;                        // pre: 4*B*256 f32 (32 MB)
  const size_t preBytes = (size_t)4 * B * 256 * 4;
  unsigned short* frB = (unsigned short*)((char*)d_ws + preBytes);
  unsigned short* sBs = frB + 2 * FR_SIDE;         // 592 tiles * 512 u16
  size_t epsOff = preBytes + (size_t)2 * FR_SIDE * 2 + (size_t)592 * 512 * 2;
  epsOff = (epsOff + 255) & ~(size_t)255;
  const unsigned ndBN = (unsigned)((size_t)nd * B * 64);
  float* epsBuf = (float*)((char*)d_ws + epsOff);
  const bool useEps = ws_size >= epsOff + (size_t)2 * ndBN * 4;
  float* out = (float*)d_out;

  GeRN_prep<<<944, 64, 0, stream>>>(
      Wij, Wid, Wgj, Wgd, Wprj, Wprd, Wpoj, Wpod, Wdj, Wdd, frB, sBs);
  if (useEps) {
    GeRN_eps<<<(int)((2u * ndBN + 2047u) / 2048u), 256, 0, stream>>>(epsBuf, ndBN);
  }
  GeRN_staticM<<<B / 32, 256, 0, stream>>>(
      cnd, qj, qd, qv, bij, bid, bgj, bgd, sBs, ws, B);
  if (useEps) {
    GeRN_recur<1><<<2 * (B / 16), 256, 0, stream>>>(
        frB,
        ws, ws + (size_t)B * 256, ws + (size_t)2 * B * 256, ws + (size_t)3 * B * 256,
        bprj, bprd, bpoj, bpod, bdj, bdd,
        hi_j0, ci_j0, hi_d0, ci_d0, hg_j0, cg_j0, hg_d0, cg_d0, ug_j0, ug_d0,
        epsBuf, ndBN, out, B, nd);
  } else {
    GeRN_recur<0><<<2 * (B / 16), 256, 0, stream>>>(
        frB,
        ws, ws + (size_t)B * 256, ws + (size_t)2 * B * 256, ws + (size_t)3 * B * 256,
        bprj, bprd, bpoj, bpod, bdj, bdd,
        hi_j0, ci_j0, hi_d0, ci_d0, hg_j0, cg_j0, hg_d0, cg_d0, ug_j0, ug_d0,
        (const float*)0, ndBN, out, B, nd);
  }
}